// Round 1
// baseline (8608.115 us; speedup 1.0000x reference)
//
#include <hip/hip_runtime.h>
#include <hip/hip_bf16.h>

#define NN 100000
#define NE 1600000
#define DD 128
#define NL 3
#define NG 512

typedef __attribute__((ext_vector_type(8))) short bf16x8;
typedef __attribute__((ext_vector_type(4))) float f32x4;

__device__ __forceinline__ unsigned short f2bf(float f) {
    union { float f; unsigned int u; } x; x.f = f;
    unsigned int r = x.u + 0x7FFFu + ((x.u >> 16) & 1u);
    return (unsigned short)(r >> 16);
}

// Convert W1,W2 (f32 [L][K][N]) -> bf16 transposed [l][which][n][k]
__global__ __launch_bounds__(256) void prep_w(const float* __restrict__ W1,
                                              const float* __restrict__ W2,
                                              unsigned short* __restrict__ wbf) {
    int idx = blockIdx.x * 256 + threadIdx.x;   // < NL*2*DD*DD
    int k = idx & 127;
    int n = (idx >> 7) & 127;
    int w = (idx >> 14) & 1;
    int l = idx >> 15;
    const float* src = w ? W2 : W1;
    wbf[idx] = f2bf(src[(l * DD + k) * DD + n]);
}

// agg[dst] += h[src] over all edges (atomic scatter)
__global__ __launch_bounds__(256) void scatter_agg(const float* __restrict__ h,
                                                   const int* __restrict__ ei,
                                                   float* __restrict__ agg) {
    unsigned int t = blockIdx.x * 256u + threadIdx.x;   // < NE*32
    unsigned int e = t >> 5;
    unsigned int c = (t & 31u) << 2;
    int s = ei[e];
    int d = ei[NE + e];
    const float4 v = *reinterpret_cast<const float4*>(h + (size_t)s * DD + c);
    float* a = agg + (size_t)d * DD + c;
    atomicAdd(a + 0, v.x);
    atomicAdd(a + 1, v.y);
    atomicAdd(a + 2, v.z);
    atomicAdd(a + 3, v.w);
}

// Fused per-layer: z=(1+eps)*h+agg; z1=relu(z@W1+b1); z2=relu(z1@W2+b2); h=BN(z2)
__global__ __launch_bounds__(256) void layer_fused(
    const float* __restrict__ hin,
    const float* __restrict__ agg,
    const unsigned short* __restrict__ w1t,   // [n][k] bf16
    const unsigned short* __restrict__ w2t,   // [n][k] bf16
    const float* __restrict__ b1,
    const float* __restrict__ b2,
    const float* __restrict__ gamma,
    const float* __restrict__ beta,
    const float* __restrict__ rmean,
    const float* __restrict__ rvar,
    const float* __restrict__ epsv,
    float* __restrict__ hout)
{
    __shared__ unsigned short z_lds[64 * 136];   // padded stride 136 bf16
    __shared__ unsigned short w_lds[128 * 136];
    const int tid = threadIdx.x;
    const int row0 = blockIdx.x * 64;
    const float epl = 1.0f + epsv[0];

    // Phase 1: z tile (64 rows) -> LDS bf16
    #pragma unroll
    for (int i = 0; i < 8; ++i) {
        int idx = tid + i * 256;
        int r = idx >> 5;
        int c = (idx & 31) << 2;
        int gr = row0 + r;
        float4 hv = {0,0,0,0}, av = {0,0,0,0};
        if (gr < NN) {
            hv = *reinterpret_cast<const float4*>(hin + (size_t)gr * DD + c);
            av = *reinterpret_cast<const float4*>(agg + (size_t)gr * DD + c);
        }
        union { unsigned short s[4]; uint2 u; } pk;
        pk.s[0] = f2bf(epl * hv.x + av.x);
        pk.s[1] = f2bf(epl * hv.y + av.y);
        pk.s[2] = f2bf(epl * hv.z + av.z);
        pk.s[3] = f2bf(epl * hv.w + av.w);
        *reinterpret_cast<uint2*>(&z_lds[r * 136 + c]) = pk.u;
    }

    // Phase 2: W1T -> LDS
    #pragma unroll
    for (int i = 0; i < 8; ++i) {
        int idx = tid + i * 256;
        int r = idx >> 4;
        int c = (idx & 15) << 3;
        uint4 v = *reinterpret_cast<const uint4*>(w1t + r * DD + c);
        *reinterpret_cast<uint4*>(&w_lds[r * 136 + c]) = v;
    }
    __syncthreads();

    const int lane = tid & 63;
    const int wave = tid >> 6;
    const int l15 = lane & 15;
    const int kq = lane >> 4;                 // 0..3
    const int arow = (wave << 4) + l15;

    // Matmul 1
    bf16x8 afr[4];
    #pragma unroll
    for (int kk = 0; kk < 4; ++kk)
        afr[kk] = *reinterpret_cast<const bf16x8*>(&z_lds[arow * 136 + kk * 32 + kq * 8]);

    f32x4 acc[8];
    #pragma unroll
    for (int nt = 0; nt < 8; ++nt) acc[nt] = (f32x4){0.f, 0.f, 0.f, 0.f};
    #pragma unroll
    for (int nt = 0; nt < 8; ++nt) {
        #pragma unroll
        for (int kk = 0; kk < 4; ++kk) {
            bf16x8 bfr = *reinterpret_cast<const bf16x8*>(
                &w_lds[(nt * 16 + l15) * 136 + kk * 32 + kq * 8]);
            acc[nt] = __builtin_amdgcn_mfma_f32_16x16x32_bf16(afr[kk], bfr, acc[nt], 0, 0, 0);
        }
    }

    // Epilogue 1: bias+relu, z1 -> z_lds (own rows only)
    #pragma unroll
    for (int nt = 0; nt < 8; ++nt) {
        int col = nt * 16 + l15;
        float bv = b1[col];
        #pragma unroll
        for (int r = 0; r < 4; ++r) {
            int zr = (wave << 4) + kq * 4 + r;
            float v = acc[nt][r] + bv;
            v = v > 0.f ? v : 0.f;
            z_lds[zr * 136 + col] = f2bf(v);
        }
    }
    __syncthreads();

    // Phase 3: W2T -> LDS
    #pragma unroll
    for (int i = 0; i < 8; ++i) {
        int idx = tid + i * 256;
        int r = idx >> 4;
        int c = (idx & 15) << 3;
        uint4 v = *reinterpret_cast<const uint4*>(w2t + r * DD + c);
        *reinterpret_cast<uint4*>(&w_lds[r * 136 + c]) = v;
    }
    __syncthreads();

    // Matmul 2
    #pragma unroll
    for (int kk = 0; kk < 4; ++kk)
        afr[kk] = *reinterpret_cast<const bf16x8*>(&z_lds[arow * 136 + kk * 32 + kq * 8]);
    #pragma unroll
    for (int nt = 0; nt < 8; ++nt) acc[nt] = (f32x4){0.f, 0.f, 0.f, 0.f};
    #pragma unroll
    for (int nt = 0; nt < 8; ++nt) {
        #pragma unroll
        for (int kk = 0; kk < 4; ++kk) {
            bf16x8 bfr = *reinterpret_cast<const bf16x8*>(
                &w_lds[(nt * 16 + l15) * 136 + kk * 32 + kq * 8]);
            acc[nt] = __builtin_amdgcn_mfma_f32_16x16x32_bf16(afr[kk], bfr, acc[nt], 0, 0, 0);
        }
    }

    // Epilogue 2: bias+relu+BN -> global
    #pragma unroll
    for (int nt = 0; nt < 8; ++nt) {
        int col = nt * 16 + l15;
        float bv = b2[col];
        float ga = gamma[col];
        float be = beta[col];
        float mu = rmean[col];
        float inv = rsqrtf(rvar[col] + 1e-5f);
        #pragma unroll
        for (int r = 0; r < 4; ++r) {
            int zr = (wave << 4) + kq * 4 + r;
            int gr = row0 + zr;
            if (gr < NN) {
                float v = acc[nt][r] + bv;
                v = v > 0.f ? v : 0.f;
                v = (v - mu) * inv * ga + be;
                hout[(size_t)gr * DD + col] = v;
            }
        }
    }
}

__global__ __launch_bounds__(256) void pool_kernel(const float* __restrict__ h,
                                                   const int* __restrict__ batch,
                                                   float* __restrict__ pooled,
                                                   float* __restrict__ counts) {
    unsigned int t = blockIdx.x * 256u + threadIdx.x;   // < NN*32
    unsigned int i = t >> 5;
    if (i >= NN) return;
    unsigned int c = (t & 31u) << 2;
    int g = batch[i];
    float4 v = *reinterpret_cast<const float4*>(h + (size_t)i * DD + c);
    float* p = pooled + (size_t)g * DD + c;
    atomicAdd(p + 0, v.x);
    atomicAdd(p + 1, v.y);
    atomicAdd(p + 2, v.z);
    atomicAdd(p + 3, v.w);
    if ((t & 31u) == 0) atomicAdd(counts + g, 1.0f);
}

__global__ __launch_bounds__(256) void final_kernel(const float* __restrict__ pooled,
                                                    const float* __restrict__ counts,
                                                    const float* __restrict__ W,
                                                    const float* __restrict__ b,
                                                    float* __restrict__ out) {
    int t = blockIdx.x * 256 + threadIdx.x;   // < NG*DD
    int g = t >> 7;
    int n = t & 127;
    float inv = 1.0f / fmaxf(counts[g], 1.0f);
    float s = b[n];
    const float* pr = pooled + (size_t)g * DD;
    #pragma unroll 4
    for (int k = 0; k < DD; ++k)
        s += (pr[k] * inv) * W[k * DD + n];
    out[t] = fmaxf(s, 0.0f);
}

extern "C" void kernel_launch(void* const* d_in, const int* in_sizes, int n_in,
                              void* d_out, int out_size, void* d_ws, size_t ws_size,
                              hipStream_t stream) {
    const float* x     = (const float*)d_in[0];
    const int*   ei    = (const int*)d_in[1];
    const int*   batch = (const int*)d_in[2];
    const float* W1    = (const float*)d_in[3];
    const float* b1    = (const float*)d_in[4];
    const float* W2    = (const float*)d_in[5];
    const float* b2    = (const float*)d_in[6];
    const float* gamma = (const float*)d_in[7];
    const float* beta  = (const float*)d_in[8];
    const float* rmean = (const float*)d_in[9];
    const float* rvar  = (const float*)d_in[10];
    const float* eps   = (const float*)d_in[11];
    const float* lin1W = (const float*)d_in[12];
    const float* lin1b = (const float*)d_in[13];
    float* out = (float*)d_out;

    char* ws = (char*)d_ws;
    size_t off = 0;
    float* agg = (float*)(ws + off);    off += (size_t)NN * DD * 4;
    float* hbuf = (float*)(ws + off);   off += (size_t)NN * DD * 4;
    float* pooled = (float*)(ws + off); off += (size_t)NG * DD * 4;
    float* counts = (float*)(ws + off); off += (size_t)NG * 4;
    unsigned short* wbf = (unsigned short*)(ws + off); off += (size_t)NL * 2 * DD * DD * 2;

    prep_w<<<NL * 2 * DD * DD / 256, 256, 0, stream>>>(W1, W2, wbf);

    const float* hcur = x;
    for (int l = 0; l < NL; ++l) {
        hipMemsetAsync(agg, 0, (size_t)NN * DD * 4, stream);
        scatter_agg<<<NE * 32 / 256, 256, 0, stream>>>(hcur, ei, agg);
        layer_fused<<<(NN + 63) / 64, 256, 0, stream>>>(
            hcur, agg,
            wbf + (size_t)(l * 2 + 0) * DD * DD,
            wbf + (size_t)(l * 2 + 1) * DD * DD,
            b1 + l * DD, b2 + l * DD,
            gamma + l * DD, beta + l * DD,
            rmean + l * DD, rvar + l * DD,
            eps + l,
            hbuf);
        hcur = hbuf;
    }

    hipMemsetAsync(pooled, 0, (size_t)(NG * DD + NG) * 4, stream);
    pool_kernel<<<NN * 32 / 256, 256, 0, stream>>>(hbuf, batch, pooled, counts);
    final_kernel<<<NG * DD / 256, 256, 0, stream>>>(pooled, counts, lin1W, lin1b, out);
}

// Round 2
// 1536.910 us; speedup vs baseline: 5.6009x; 5.6009x over previous
//
#include <hip/hip_runtime.h>
#include <hip/hip_bf16.h>

#define NN 100000
#define NE 1600000
#define DD 128
#define NL 3
#define NG 512
#define NBLK ((NN + 255) / 256)   // 391 scan blocks

typedef __attribute__((ext_vector_type(8))) short bf16x8;
typedef __attribute__((ext_vector_type(4))) float f32x4;

__device__ __forceinline__ unsigned short f2bf(float f) {
    union { float f; unsigned int u; } x; x.f = f;
    unsigned int r = x.u + 0x7FFFu + ((x.u >> 16) & 1u);
    return (unsigned short)(r >> 16);
}
__device__ __forceinline__ float bf2f(unsigned short u) {
    union { unsigned int u; float f; } x; x.u = ((unsigned int)u) << 16;
    return x.f;
}

// Convert W1,W2 (f32 [L][K][N]) -> bf16 transposed [l][which][n][k]
__global__ __launch_bounds__(256) void prep_w(const float* __restrict__ W1,
                                              const float* __restrict__ W2,
                                              unsigned short* __restrict__ wbf) {
    int idx = blockIdx.x * 256 + threadIdx.x;
    int k = idx & 127;
    int n = (idx >> 7) & 127;
    int w = (idx >> 14) & 1;
    int l = idx >> 15;
    const float* src = w ? W2 : W1;
    wbf[idx] = f2bf(src[(l * DD + k) * DD + n]);
}

// ---------------- CSR build (once per call) ----------------
__global__ __launch_bounds__(256) void hist_deg(const int* __restrict__ ei,
                                                int* __restrict__ deg) {
    unsigned int e = blockIdx.x * 256u + threadIdx.x;   // < NE
    atomicAdd(&deg[ei[NE + e]], 1);
}

__global__ __launch_bounds__(256) void scan1(const int* __restrict__ deg,
                                             int* __restrict__ rp,
                                             int* __restrict__ part) {
    __shared__ int s[256];
    int tid = threadIdx.x;
    int i = blockIdx.x * 256 + tid;
    int v = (i < NN) ? deg[i] : 0;
    s[tid] = v;
    __syncthreads();
    for (int o = 1; o < 256; o <<= 1) {
        int t = (tid >= o) ? s[tid - o] : 0;
        __syncthreads();
        s[tid] += t;
        __syncthreads();
    }
    if (i < NN) rp[i] = s[tid] - v;     // exclusive, block-local
    if (tid == 255) part[blockIdx.x] = s[255];
}

__global__ __launch_bounds__(512) void scan2(int* __restrict__ part) {
    __shared__ int s[512];
    int tid = threadIdx.x;
    int v = (tid < NBLK) ? part[tid] : 0;
    s[tid] = v;
    __syncthreads();
    for (int o = 1; o < 512; o <<= 1) {
        int t = (tid >= o) ? s[tid - o] : 0;
        __syncthreads();
        s[tid] += t;
        __syncthreads();
    }
    if (tid < NBLK) part[tid] = s[tid] - v;   // exclusive over blocks
}

__global__ __launch_bounds__(256) void scan3(int* __restrict__ rp,
                                             const int* __restrict__ part,
                                             int* __restrict__ cnt) {
    int i = blockIdx.x * 256 + threadIdx.x;
    if (i < NN) {
        rp[i] += part[i >> 8];
        cnt[i] = 0;
    }
    if (i == 0) rp[NN] = NE;
}

__global__ __launch_bounds__(256) void fill_csr(const int* __restrict__ ei,
                                                const int* __restrict__ rp,
                                                int* __restrict__ cnt,
                                                int* __restrict__ csr) {
    unsigned int e = blockIdx.x * 256u + threadIdx.x;   // < NE
    int s = ei[e];
    int d = ei[NE + e];
    int pos = atomicAdd(&cnt[d], 1);
    csr[rp[d] + pos] = s;
}

// ---------------- fused layer: gather-agg + MLP + BN ----------------
// hin: f32 (layer 0) or bf16; hout: bf16
template <bool INF32>
__global__ __launch_bounds__(256) void layer_fused(
    const void* __restrict__ hin_v,
    const int* __restrict__ rp,
    const int* __restrict__ csr,
    const unsigned short* __restrict__ w1t,   // [n][k] bf16
    const unsigned short* __restrict__ w2t,   // [n][k] bf16
    const float* __restrict__ b1,
    const float* __restrict__ b2,
    const float* __restrict__ gamma,
    const float* __restrict__ beta,
    const float* __restrict__ rmean,
    const float* __restrict__ rvar,
    const float* __restrict__ epsv,
    unsigned short* __restrict__ hout)
{
    __shared__ unsigned short z_lds[64 * 136];
    __shared__ unsigned short w_lds[128 * 136];
    const int tid = threadIdx.x;
    const int lane = tid & 63;
    const int wave = tid >> 6;
    const int row0 = blockIdx.x * 64;
    const float epl = 1.0f + epsv[0];

    const float* hf = (const float*)hin_v;
    const unsigned short* hb = (const unsigned short*)hin_v;

    // Phase 1: gather-aggregate 16 rows per wave -> z tile bf16 in LDS
    for (int rr = 0; rr < 16; ++rr) {
        int r = (wave << 4) + rr;
        int gr = row0 + r;
        float2 acc = {0.f, 0.f};
        if (gr < NN) {
            float2 hv;
            if (INF32) {
                hv = *reinterpret_cast<const float2*>(hf + (size_t)gr * DD + lane * 2);
            } else {
                ushort2 u = *reinterpret_cast<const ushort2*>(hb + (size_t)gr * DD + lane * 2);
                hv.x = bf2f(u.x); hv.y = bf2f(u.y);
            }
            acc.x = epl * hv.x;
            acc.y = epl * hv.y;
            int st = rp[gr], en = rp[gr + 1];
            for (int c0 = st; c0 < en; c0 += 64) {
                int m = en - c0;
                int lim = m < 64 ? m : 64;
                int my = (lane < lim) ? csr[c0 + lane] : 0;
                for (int j = 0; j < lim; ++j) {
                    int s = __shfl(my, j);
                    if (INF32) {
                        float2 v = *reinterpret_cast<const float2*>(hf + (size_t)s * DD + lane * 2);
                        acc.x += v.x; acc.y += v.y;
                    } else {
                        ushort2 u = *reinterpret_cast<const ushort2*>(hb + (size_t)s * DD + lane * 2);
                        acc.x += bf2f(u.x); acc.y += bf2f(u.y);
                    }
                }
            }
        }
        ushort2 pk;
        pk.x = f2bf(acc.x);
        pk.y = f2bf(acc.y);
        *reinterpret_cast<ushort2*>(&z_lds[r * 136 + lane * 2]) = pk;
    }

    // Phase 2: W1T -> LDS
    #pragma unroll
    for (int i = 0; i < 8; ++i) {
        int idx = tid + i * 256;
        int r = idx >> 4;
        int c = (idx & 15) << 3;
        uint4 v = *reinterpret_cast<const uint4*>(w1t + r * DD + c);
        *reinterpret_cast<uint4*>(&w_lds[r * 136 + c]) = v;
    }
    __syncthreads();

    const int l15 = lane & 15;
    const int kq = lane >> 4;
    const int arow = (wave << 4) + l15;

    // Matmul 1
    bf16x8 afr[4];
    #pragma unroll
    for (int kk = 0; kk < 4; ++kk)
        afr[kk] = *reinterpret_cast<const bf16x8*>(&z_lds[arow * 136 + kk * 32 + kq * 8]);

    f32x4 acc[8];
    #pragma unroll
    for (int nt = 0; nt < 8; ++nt) acc[nt] = (f32x4){0.f, 0.f, 0.f, 0.f};
    #pragma unroll
    for (int nt = 0; nt < 8; ++nt) {
        #pragma unroll
        for (int kk = 0; kk < 4; ++kk) {
            bf16x8 bfr = *reinterpret_cast<const bf16x8*>(
                &w_lds[(nt * 16 + l15) * 136 + kk * 32 + kq * 8]);
            acc[nt] = __builtin_amdgcn_mfma_f32_16x16x32_bf16(afr[kk], bfr, acc[nt], 0, 0, 0);
        }
    }

    // Epilogue 1: bias+relu, z1 -> z_lds (own wave's 16-row stripe only)
    #pragma unroll
    for (int nt = 0; nt < 8; ++nt) {
        int col = nt * 16 + l15;
        float bv = b1[col];
        #pragma unroll
        for (int r = 0; r < 4; ++r) {
            int zr = (wave << 4) + kq * 4 + r;
            float v = acc[nt][r] + bv;
            v = v > 0.f ? v : 0.f;
            z_lds[zr * 136 + col] = f2bf(v);
        }
    }
    __syncthreads();

    // Phase 3: W2T -> LDS
    #pragma unroll
    for (int i = 0; i < 8; ++i) {
        int idx = tid + i * 256;
        int r = idx >> 4;
        int c = (idx & 15) << 3;
        uint4 v = *reinterpret_cast<const uint4*>(w2t + r * DD + c);
        *reinterpret_cast<uint4*>(&w_lds[r * 136 + c]) = v;
    }
    __syncthreads();

    // Matmul 2
    #pragma unroll
    for (int kk = 0; kk < 4; ++kk)
        afr[kk] = *reinterpret_cast<const bf16x8*>(&z_lds[arow * 136 + kk * 32 + kq * 8]);
    #pragma unroll
    for (int nt = 0; nt < 8; ++nt) acc[nt] = (f32x4){0.f, 0.f, 0.f, 0.f};
    #pragma unroll
    for (int nt = 0; nt < 8; ++nt) {
        #pragma unroll
        for (int kk = 0; kk < 4; ++kk) {
            bf16x8 bfr = *reinterpret_cast<const bf16x8*>(
                &w_lds[(nt * 16 + l15) * 136 + kk * 32 + kq * 8]);
            acc[nt] = __builtin_amdgcn_mfma_f32_16x16x32_bf16(afr[kk], bfr, acc[nt], 0, 0, 0);
        }
    }

    // Epilogue 2: bias+relu+BN -> hout (bf16)
    #pragma unroll
    for (int nt = 0; nt < 8; ++nt) {
        int col = nt * 16 + l15;
        float bv = b2[col];
        float ga = gamma[col];
        float be = beta[col];
        float mu = rmean[col];
        float inv = rsqrtf(rvar[col] + 1e-5f);
        #pragma unroll
        for (int r = 0; r < 4; ++r) {
            int zr = (wave << 4) + kq * 4 + r;
            int gr = row0 + zr;
            if (gr < NN) {
                float v = acc[nt][r] + bv;
                v = v > 0.f ? v : 0.f;
                v = (v - mu) * inv * ga + be;
                hout[(size_t)gr * DD + col] = f2bf(v);
            }
        }
    }
}

__global__ __launch_bounds__(256) void pool_kernel(const unsigned short* __restrict__ h,
                                                   const int* __restrict__ batch,
                                                   float* __restrict__ pooled,
                                                   float* __restrict__ counts) {
    unsigned int t = blockIdx.x * 256u + threadIdx.x;   // < NN*32
    unsigned int i = t >> 5;
    if (i >= NN) return;
    unsigned int c = (t & 31u) << 2;
    int g = batch[i];
    ushort4 u = *reinterpret_cast<const ushort4*>(h + (size_t)i * DD + c);
    float* p = pooled + (size_t)g * DD + c;
    atomicAdd(p + 0, bf2f(u.x));
    atomicAdd(p + 1, bf2f(u.y));
    atomicAdd(p + 2, bf2f(u.z));
    atomicAdd(p + 3, bf2f(u.w));
    if ((t & 31u) == 0) atomicAdd(counts + g, 1.0f);
}

__global__ __launch_bounds__(256) void final_kernel(const float* __restrict__ pooled,
                                                    const float* __restrict__ counts,
                                                    const float* __restrict__ W,
                                                    const float* __restrict__ b,
                                                    float* __restrict__ out) {
    int t = blockIdx.x * 256 + threadIdx.x;   // < NG*DD
    int g = t >> 7;
    int n = t & 127;
    float inv = 1.0f / fmaxf(counts[g], 1.0f);
    float s = b[n];
    const float* pr = pooled + (size_t)g * DD;
    #pragma unroll 4
    for (int k = 0; k < DD; ++k)
        s += (pr[k] * inv) * W[k * DD + n];
    out[t] = fmaxf(s, 0.0f);
}

extern "C" void kernel_launch(void* const* d_in, const int* in_sizes, int n_in,
                              void* d_out, int out_size, void* d_ws, size_t ws_size,
                              hipStream_t stream) {
    const float* x     = (const float*)d_in[0];
    const int*   ei    = (const int*)d_in[1];
    const int*   batch = (const int*)d_in[2];
    const float* W1    = (const float*)d_in[3];
    const float* b1    = (const float*)d_in[4];
    const float* W2    = (const float*)d_in[5];
    const float* b2    = (const float*)d_in[6];
    const float* gamma = (const float*)d_in[7];
    const float* beta  = (const float*)d_in[8];
    const float* rmean = (const float*)d_in[9];
    const float* rvar  = (const float*)d_in[10];
    const float* eps   = (const float*)d_in[11];
    const float* lin1W = (const float*)d_in[12];
    const float* lin1b = (const float*)d_in[13];
    float* out = (float*)d_out;

    char* ws = (char*)d_ws;
    size_t off = 0;
    auto alloc = [&](size_t bytes) {
        void* p = ws + off;
        off = (off + bytes + 255) & ~(size_t)255;
        return p;
    };
    unsigned short* hA  = (unsigned short*)alloc((size_t)NN * DD * 2);
    unsigned short* hB  = (unsigned short*)alloc((size_t)NN * DD * 2);
    int* rp   = (int*)alloc((size_t)(NN + 1) * 4);
    int* deg  = (int*)alloc((size_t)NN * 4);
    int* cnt  = (int*)alloc((size_t)NN * 4);
    int* part = (int*)alloc(512 * 4);
    int* csr  = (int*)alloc((size_t)NE * 4);
    unsigned short* wbf = (unsigned short*)alloc((size_t)NL * 2 * DD * DD * 2);
    float* pooled = (float*)alloc((size_t)NG * DD * 4);
    float* counts = (float*)alloc((size_t)NG * 4);

    prep_w<<<NL * 2 * DD * DD / 256, 256, 0, stream>>>(W1, W2, wbf);

    // CSR build (edge structure is layer-invariant)
    hipMemsetAsync(deg, 0, (size_t)NN * 4, stream);
    hist_deg<<<NE / 256, 256, 0, stream>>>(ei, deg);
    scan1<<<NBLK, 256, 0, stream>>>(deg, rp, part);
    scan2<<<1, 512, 0, stream>>>(part);
    scan3<<<NBLK, 256, 0, stream>>>(rp, part, cnt);
    fill_csr<<<NE / 256, 256, 0, stream>>>(ei, rp, cnt, csr);

    const int lgrid = (NN + 63) / 64;
    // layer 0: f32 x -> bf16 hA
    layer_fused<true><<<lgrid, 256, 0, stream>>>(
        x, rp, csr,
        wbf + 0 * DD * DD, wbf + 1 * DD * DD,
        b1 + 0 * DD, b2 + 0 * DD, gamma + 0 * DD, beta + 0 * DD,
        rmean + 0 * DD, rvar + 0 * DD, eps + 0, hA);
    // layer 1: hA -> hB
    layer_fused<false><<<lgrid, 256, 0, stream>>>(
        hA, rp, csr,
        wbf + 2 * DD * DD, wbf + 3 * DD * DD,
        b1 + 1 * DD, b2 + 1 * DD, gamma + 1 * DD, beta + 1 * DD,
        rmean + 1 * DD, rvar + 1 * DD, eps + 1, hB);
    // layer 2: hB -> hA
    layer_fused<false><<<lgrid, 256, 0, stream>>>(
        hB, rp, csr,
        wbf + 4 * DD * DD, wbf + 5 * DD * DD,
        b1 + 2 * DD, b2 + 2 * DD, gamma + 2 * DD, beta + 2 * DD,
        rmean + 2 * DD, rvar + 2 * DD, eps + 2, hA);

    hipMemsetAsync(pooled, 0, (size_t)NG * DD * 4, stream);
    hipMemsetAsync(counts, 0, (size_t)NG * 4, stream);
    pool_kernel<<<(NN * 32 + 255) / 256, 256, 0, stream>>>(hA, batch, pooled, counts);
    final_kernel<<<NG * DD / 256, 256, 0, stream>>>(pooled, counts, lin1W, lin1b, out);
}

// Round 3
// 810.469 us; speedup vs baseline: 10.6212x; 1.8963x over previous
//
#include <hip/hip_runtime.h>
#include <hip/hip_bf16.h>

#define NN 100000
#define NE 1600000
#define DD 128
#define NL 3
#define NG 512
#define NBLK ((NN + 255) / 256)   // 391 scan blocks

typedef __attribute__((ext_vector_type(8))) short bf16x8;
typedef __attribute__((ext_vector_type(4))) float f32x4;

__device__ __forceinline__ unsigned short f2bf(float f) {
    union { float f; unsigned int u; } x; x.f = f;
    unsigned int r = x.u + 0x7FFFu + ((x.u >> 16) & 1u);
    return (unsigned short)(r >> 16);
}
__device__ __forceinline__ float bf2f(unsigned short u) {
    union { unsigned int u; float f; } x; x.u = ((unsigned int)u) << 16;
    return x.f;
}
__device__ __forceinline__ float bflo(unsigned int v) { return bf2f((unsigned short)(v & 0xffffu)); }
__device__ __forceinline__ float bfhi(unsigned int v) { return bf2f((unsigned short)(v >> 16)); }

// Convert W1,W2 (f32 [L][K][N]) -> bf16 transposed [l][which][n][k]
__global__ __launch_bounds__(256) void prep_w(const float* __restrict__ W1,
                                              const float* __restrict__ W2,
                                              unsigned short* __restrict__ wbf) {
    int idx = blockIdx.x * 256 + threadIdx.x;
    int k = idx & 127;
    int n = (idx >> 7) & 127;
    int w = (idx >> 14) & 1;
    int l = idx >> 15;
    const float* src = w ? W2 : W1;
    wbf[idx] = f2bf(src[(l * DD + k) * DD + n]);
}

// ---------------- CSR build (once per call) ----------------
__global__ __launch_bounds__(256) void hist_deg(const int* __restrict__ ei,
                                                int* __restrict__ deg) {
    unsigned int e = blockIdx.x * 256u + threadIdx.x;   // < NE
    atomicAdd(&deg[ei[NE + e]], 1);
}

__global__ __launch_bounds__(256) void scan1(const int* __restrict__ deg,
                                             int* __restrict__ rp,
                                             int* __restrict__ part) {
    __shared__ int s[256];
    int tid = threadIdx.x;
    int i = blockIdx.x * 256 + tid;
    int v = (i < NN) ? deg[i] : 0;
    s[tid] = v;
    __syncthreads();
    for (int o = 1; o < 256; o <<= 1) {
        int t = (tid >= o) ? s[tid - o] : 0;
        __syncthreads();
        s[tid] += t;
        __syncthreads();
    }
    if (i < NN) rp[i] = s[tid] - v;     // exclusive, block-local
    if (tid == 255) part[blockIdx.x] = s[255];
}

__global__ __launch_bounds__(512) void scan2(int* __restrict__ part) {
    __shared__ int s[512];
    int tid = threadIdx.x;
    int v = (tid < NBLK) ? part[tid] : 0;
    s[tid] = v;
    __syncthreads();
    for (int o = 1; o < 512; o <<= 1) {
        int t = (tid >= o) ? s[tid - o] : 0;
        __syncthreads();
        s[tid] += t;
        __syncthreads();
    }
    if (tid < NBLK) part[tid] = s[tid] - v;   // exclusive over blocks
}

__global__ __launch_bounds__(256) void scan3(int* __restrict__ rp,
                                             const int* __restrict__ part,
                                             int* __restrict__ cnt) {
    int i = blockIdx.x * 256 + threadIdx.x;
    if (i < NN) {
        rp[i] += part[i >> 8];
        cnt[i] = 0;
    }
    if (i == 0) rp[NN] = NE;
}

__global__ __launch_bounds__(256) void fill_csr(const int* __restrict__ ei,
                                                const int* __restrict__ rp,
                                                int* __restrict__ cnt,
                                                int* __restrict__ csr) {
    unsigned int e = blockIdx.x * 256u + threadIdx.x;   // < NE
    int s = ei[e];
    int d = ei[NE + e];
    int pos = atomicAdd(&cnt[d], 1);
    csr[rp[d] + pos] = s;
}

// ---------------- fused layer: gather-agg + MLP + BN ----------------
// hin: f32 (layer 0) or bf16; hout: bf16
template <bool INF32>
__global__ __launch_bounds__(256) void layer_fused(
    const void* __restrict__ hin_v,
    const int* __restrict__ rp,
    const int* __restrict__ csr,
    const unsigned short* __restrict__ w1t,   // [n][k] bf16
    const unsigned short* __restrict__ w2t,   // [n][k] bf16
    const float* __restrict__ b1,
    const float* __restrict__ b2,
    const float* __restrict__ gamma,
    const float* __restrict__ beta,
    const float* __restrict__ rmean,
    const float* __restrict__ rvar,
    const float* __restrict__ epsv,
    unsigned short* __restrict__ hout)
{
    __shared__ unsigned short z_lds[64 * 136];
    __shared__ unsigned short w_lds[128 * 136];
    const int tid = threadIdx.x;
    const int lane = tid & 63;
    const int wave = tid >> 6;
    const int row0 = blockIdx.x * 64;
    const float epl = 1.0f + epsv[0];

    const float* hf = (const float*)hin_v;
    const unsigned short* hb = (const unsigned short*)hin_v;

    // Phase 1: gather-aggregate 16 rows per wave -> z tile bf16 in LDS
    // MLP x8: batch 8 independent loads before accumulating.
    for (int rr = 0; rr < 16; ++rr) {
        int r = (wave << 4) + rr;
        int gr = row0 + r;
        float2 a[4];
        #pragma unroll
        for (int q = 0; q < 4; ++q) a[q] = (float2){0.f, 0.f};
        if (gr < NN) {
            if (INF32) {
                float2 hv = *reinterpret_cast<const float2*>(hf + (size_t)gr * DD + lane * 2);
                a[0].x = epl * hv.x; a[0].y = epl * hv.y;
            } else {
                unsigned int u = *reinterpret_cast<const unsigned int*>(hb + (size_t)gr * DD + lane * 2);
                a[0].x = epl * bflo(u); a[0].y = epl * bfhi(u);
            }
            int st = rp[gr], en = rp[gr + 1];
            for (int c0 = st; c0 < en; c0 += 64) {
                int m = en - c0;
                int lim = m < 64 ? m : 64;
                int my = (lane < lim) ? csr[c0 + lane] : 0;
                int j = 0;
                for (; j + 8 <= lim; j += 8) {
                    int sidx[8];
                    #pragma unroll
                    for (int q = 0; q < 8; ++q) sidx[q] = __shfl(my, j + q);
                    if (INF32) {
                        float2 v[8];
                        #pragma unroll
                        for (int q = 0; q < 8; ++q)
                            v[q] = *reinterpret_cast<const float2*>(hf + (size_t)sidx[q] * DD + lane * 2);
                        #pragma unroll
                        for (int q = 0; q < 8; ++q) {
                            a[q & 3].x += v[q].x;
                            a[q & 3].y += v[q].y;
                        }
                    } else {
                        unsigned int v[8];
                        #pragma unroll
                        for (int q = 0; q < 8; ++q)
                            v[q] = *reinterpret_cast<const unsigned int*>(hb + (size_t)sidx[q] * DD + lane * 2);
                        #pragma unroll
                        for (int q = 0; q < 8; ++q) {
                            a[q & 3].x += bflo(v[q]);
                            a[q & 3].y += bfhi(v[q]);
                        }
                    }
                }
                for (; j < lim; ++j) {
                    int s = __shfl(my, j);
                    if (INF32) {
                        float2 v = *reinterpret_cast<const float2*>(hf + (size_t)s * DD + lane * 2);
                        a[0].x += v.x; a[0].y += v.y;
                    } else {
                        unsigned int u = *reinterpret_cast<const unsigned int*>(hb + (size_t)s * DD + lane * 2);
                        a[0].x += bflo(u); a[0].y += bfhi(u);
                    }
                }
            }
        }
        float accx = (a[0].x + a[1].x) + (a[2].x + a[3].x);
        float accy = (a[0].y + a[1].y) + (a[2].y + a[3].y);
        ushort2 pk;
        pk.x = f2bf(accx);
        pk.y = f2bf(accy);
        *reinterpret_cast<ushort2*>(&z_lds[r * 136 + lane * 2]) = pk;
    }

    // Phase 2: W1T -> LDS
    #pragma unroll
    for (int i = 0; i < 8; ++i) {
        int idx = tid + i * 256;
        int r = idx >> 4;
        int c = (idx & 15) << 3;
        uint4 v = *reinterpret_cast<const uint4*>(w1t + r * DD + c);
        *reinterpret_cast<uint4*>(&w_lds[r * 136 + c]) = v;
    }
    __syncthreads();

    const int l15 = lane & 15;
    const int kq = lane >> 4;
    const int arow = (wave << 4) + l15;

    // Matmul 1
    bf16x8 afr[4];
    #pragma unroll
    for (int kk = 0; kk < 4; ++kk)
        afr[kk] = *reinterpret_cast<const bf16x8*>(&z_lds[arow * 136 + kk * 32 + kq * 8]);

    f32x4 acc[8];
    #pragma unroll
    for (int nt = 0; nt < 8; ++nt) acc[nt] = (f32x4){0.f, 0.f, 0.f, 0.f};
    #pragma unroll
    for (int nt = 0; nt < 8; ++nt) {
        #pragma unroll
        for (int kk = 0; kk < 4; ++kk) {
            bf16x8 bfr = *reinterpret_cast<const bf16x8*>(
                &w_lds[(nt * 16 + l15) * 136 + kk * 32 + kq * 8]);
            acc[nt] = __builtin_amdgcn_mfma_f32_16x16x32_bf16(afr[kk], bfr, acc[nt], 0, 0, 0);
        }
    }

    // Epilogue 1: bias+relu, z1 -> z_lds (own wave's 16-row stripe only)
    #pragma unroll
    for (int nt = 0; nt < 8; ++nt) {
        int col = nt * 16 + l15;
        float bv = b1[col];
        #pragma unroll
        for (int r = 0; r < 4; ++r) {
            int zr = (wave << 4) + kq * 4 + r;
            float v = acc[nt][r] + bv;
            v = v > 0.f ? v : 0.f;
            z_lds[zr * 136 + col] = f2bf(v);
        }
    }
    __syncthreads();

    // Phase 3: W2T -> LDS
    #pragma unroll
    for (int i = 0; i < 8; ++i) {
        int idx = tid + i * 256;
        int r = idx >> 4;
        int c = (idx & 15) << 3;
        uint4 v = *reinterpret_cast<const uint4*>(w2t + r * DD + c);
        *reinterpret_cast<uint4*>(&w_lds[r * 136 + c]) = v;
    }
    __syncthreads();

    // Matmul 2
    #pragma unroll
    for (int kk = 0; kk < 4; ++kk)
        afr[kk] = *reinterpret_cast<const bf16x8*>(&z_lds[arow * 136 + kk * 32 + kq * 8]);
    #pragma unroll
    for (int nt = 0; nt < 8; ++nt) acc[nt] = (f32x4){0.f, 0.f, 0.f, 0.f};
    #pragma unroll
    for (int nt = 0; nt < 8; ++nt) {
        #pragma unroll
        for (int kk = 0; kk < 4; ++kk) {
            bf16x8 bfr = *reinterpret_cast<const bf16x8*>(
                &w_lds[(nt * 16 + l15) * 136 + kk * 32 + kq * 8]);
            acc[nt] = __builtin_amdgcn_mfma_f32_16x16x32_bf16(afr[kk], bfr, acc[nt], 0, 0, 0);
        }
    }

    // Epilogue 2: bias+relu+BN -> hout (bf16)
    #pragma unroll
    for (int nt = 0; nt < 8; ++nt) {
        int col = nt * 16 + l15;
        float bv = b2[col];
        float ga = gamma[col];
        float be = beta[col];
        float mu = rmean[col];
        float inv = rsqrtf(rvar[col] + 1e-5f);
        #pragma unroll
        for (int r = 0; r < 4; ++r) {
            int zr = (wave << 4) + kq * 4 + r;
            int gr = row0 + zr;
            if (gr < NN) {
                float v = acc[nt][r] + bv;
                v = v > 0.f ? v : 0.f;
                v = (v - mu) * inv * ga + be;
                hout[(size_t)gr * DD + col] = f2bf(v);
            }
        }
    }
}

// ---------------- pool (sorted batch -> segment sums) + final linear ----------------
__global__ __launch_bounds__(256) void pool_final(const unsigned short* __restrict__ h,
                                                  const int* __restrict__ batch,
                                                  const float* __restrict__ W,
                                                  const float* __restrict__ b,
                                                  float* __restrict__ out) {
    int g = blockIdx.x;           // one block per graph
    int t = threadIdx.x;          // 256 threads
    int c = t & 127;
    int half = t >> 7;

    // lower_bound(batch, g) and lower_bound(batch, g+1)
    int lo = 0, hi = NN;
    while (lo < hi) { int mid = (lo + hi) >> 1; if (batch[mid] < g) lo = mid + 1; else hi = mid; }
    int start = lo;
    hi = NN;
    while (lo < hi) { int mid = (lo + hi) >> 1; if (batch[mid] < g + 1) lo = mid + 1; else hi = mid; }
    int end = lo;

    float s = 0.f;
    for (int i = start + half; i < end; i += 2)
        s += bf2f(h[(size_t)i * DD + c]);

    __shared__ float ps[2][DD];
    ps[half][c] = s;
    __syncthreads();
    if (half == 0) {
        float cnt = (float)(end - start);
        float pooled = (ps[0][c] + ps[1][c]) / fmaxf(cnt, 1.0f);
        ps[0][c] = pooled;
    }
    __syncthreads();
    if (half == 0) {
        float o = b[c];
        #pragma unroll 8
        for (int k = 0; k < DD; ++k)
            o += ps[0][k] * W[k * DD + c];
        out[(size_t)g * DD + c] = fmaxf(o, 0.f);
    }
}

extern "C" void kernel_launch(void* const* d_in, const int* in_sizes, int n_in,
                              void* d_out, int out_size, void* d_ws, size_t ws_size,
                              hipStream_t stream) {
    const float* x     = (const float*)d_in[0];
    const int*   ei    = (const int*)d_in[1];
    const int*   batch = (const int*)d_in[2];
    const float* W1    = (const float*)d_in[3];
    const float* b1    = (const float*)d_in[4];
    const float* W2    = (const float*)d_in[5];
    const float* b2    = (const float*)d_in[6];
    const float* gamma = (const float*)d_in[7];
    const float* beta  = (const float*)d_in[8];
    const float* rmean = (const float*)d_in[9];
    const float* rvar  = (const float*)d_in[10];
    const float* eps   = (const float*)d_in[11];
    const float* lin1W = (const float*)d_in[12];
    const float* lin1b = (const float*)d_in[13];
    float* out = (float*)d_out;

    char* ws = (char*)d_ws;
    size_t off = 0;
    auto alloc = [&](size_t bytes) {
        void* p = ws + off;
        off = (off + bytes + 255) & ~(size_t)255;
        return p;
    };
    unsigned short* hA  = (unsigned short*)alloc((size_t)NN * DD * 2);
    unsigned short* hB  = (unsigned short*)alloc((size_t)NN * DD * 2);
    int* rp   = (int*)alloc((size_t)(NN + 1) * 4);
    int* deg  = (int*)alloc((size_t)NN * 4);
    int* cnt  = (int*)alloc((size_t)NN * 4);
    int* part = (int*)alloc(512 * 4);
    int* csr  = (int*)alloc((size_t)NE * 4);
    unsigned short* wbf = (unsigned short*)alloc((size_t)NL * 2 * DD * DD * 2);

    prep_w<<<NL * 2 * DD * DD / 256, 256, 0, stream>>>(W1, W2, wbf);

    // CSR build (edge structure is layer-invariant)
    hipMemsetAsync(deg, 0, (size_t)NN * 4, stream);
    hist_deg<<<NE / 256, 256, 0, stream>>>(ei, deg);
    scan1<<<NBLK, 256, 0, stream>>>(deg, rp, part);
    scan2<<<1, 512, 0, stream>>>(part);
    scan3<<<NBLK, 256, 0, stream>>>(rp, part, cnt);
    fill_csr<<<NE / 256, 256, 0, stream>>>(ei, rp, cnt, csr);

    const int lgrid = (NN + 63) / 64;
    // layer 0: f32 x -> bf16 hA
    layer_fused<true><<<lgrid, 256, 0, stream>>>(
        x, rp, csr,
        wbf + 0 * DD * DD, wbf + 1 * DD * DD,
        b1 + 0 * DD, b2 + 0 * DD, gamma + 0 * DD, beta + 0 * DD,
        rmean + 0 * DD, rvar + 0 * DD, eps + 0, hA);
    // layer 1: hA -> hB
    layer_fused<false><<<lgrid, 256, 0, stream>>>(
        hA, rp, csr,
        wbf + 2 * DD * DD, wbf + 3 * DD * DD,
        b1 + 1 * DD, b2 + 1 * DD, gamma + 1 * DD, beta + 1 * DD,
        rmean + 1 * DD, rvar + 1 * DD, eps + 1, hB);
    // layer 2: hB -> hA
    layer_fused<false><<<lgrid, 256, 0, stream>>>(
        hB, rp, csr,
        wbf + 4 * DD * DD, wbf + 5 * DD * DD,
        b1 + 2 * DD, b2 + 2 * DD, gamma + 2 * DD, beta + 2 * DD,
        rmean + 2 * DD, rvar + 2 * DD, eps + 2, hA);

    pool_final<<<NG, 256, 0, stream>>>(hA, batch, lin1W, lin1b, out);
}

// Round 4
// 729.227 us; speedup vs baseline: 11.8044x; 1.1114x over previous
//
#include <hip/hip_runtime.h>
#include <hip/hip_bf16.h>

#define NN 100000
#define NE 1600000
#define DD 128
#define NL 3
#define NG 512
#define NBLK ((NN + 255) / 256)        // 391 scan blocks
#define CSRP (NE + 16 * NN)            // padded CSR capacity (ints)

typedef __attribute__((ext_vector_type(8))) short bf16x8;
typedef __attribute__((ext_vector_type(4))) float f32x4;

__device__ __forceinline__ unsigned short f2bf(float f) {
    union { float f; unsigned int u; } x; x.f = f;
    unsigned int r = x.u + 0x7FFFu + ((x.u >> 16) & 1u);
    return (unsigned short)(r >> 16);
}
__device__ __forceinline__ float bf2f(unsigned short u) {
    union { unsigned int u; float f; } x; x.u = ((unsigned int)u) << 16;
    return x.f;
}
__device__ __forceinline__ float bflo(unsigned int v) { return bf2f((unsigned short)(v & 0xffffu)); }
__device__ __forceinline__ float bfhi(unsigned int v) { return bf2f((unsigned short)(v >> 16)); }

// Convert W1,W2 (f32 [L][K][N]) -> bf16 transposed [l][which][n][k]
__global__ __launch_bounds__(256) void prep_w(const float* __restrict__ W1,
                                              const float* __restrict__ W2,
                                              unsigned short* __restrict__ wbf) {
    int idx = blockIdx.x * 256 + threadIdx.x;
    int k = idx & 127;
    int n = (idx >> 7) & 127;
    int w = (idx >> 14) & 1;
    int l = idx >> 15;
    const float* src = w ? W2 : W1;
    wbf[idx] = f2bf(src[(l * DD + k) * DD + n]);
}

// x (f32) -> h0 (bf16), and zero row NN of both h0 and h1 (dummy row)
__global__ __launch_bounds__(256) void conv_x(const float* __restrict__ x,
                                              unsigned short* __restrict__ h0,
                                              unsigned short* __restrict__ h1) {
    long long t = (long long)blockIdx.x * 256 + threadIdx.x;
    long long base = t * 4;
    if (base < (long long)NN * DD) {
        float4 v = *reinterpret_cast<const float4*>(x + base);
        ushort4 p;
        p.x = f2bf(v.x); p.y = f2bf(v.y); p.z = f2bf(v.z); p.w = f2bf(v.w);
        *reinterpret_cast<ushort4*>(h0 + base) = p;
    } else if (base < (long long)(NN + 1) * DD) {
        ushort4 z = {0, 0, 0, 0};
        *reinterpret_cast<ushort4*>(h0 + base) = z;
        *reinterpret_cast<ushort4*>(h1 + base) = z;
    }
}

// Init padded CSR with dummy index NN
__global__ __launch_bounds__(256) void fill_pad(int* __restrict__ csr) {
    unsigned int t = blockIdx.x * 256u + threadIdx.x;   // < CSRP/4
    int4 v = {NN, NN, NN, NN};
    *reinterpret_cast<int4*>(csr + (size_t)t * 4) = v;
}

// ---------------- CSR build (once per call) ----------------
__global__ __launch_bounds__(256) void hist_deg(const int* __restrict__ ei,
                                                int* __restrict__ deg) {
    unsigned int e = blockIdx.x * 256u + threadIdx.x;   // < NE
    atomicAdd(&deg[ei[NE + e]], 1);
}

// scan over PADDED degrees: pdeg = ceil(deg/16)*16
__global__ __launch_bounds__(256) void scan1(const int* __restrict__ deg,
                                             int* __restrict__ rp,
                                             int* __restrict__ part) {
    __shared__ int s[256];
    int tid = threadIdx.x;
    int i = blockIdx.x * 256 + tid;
    int v = 0;
    if (i < NN) v = (deg[i] + 15) & ~15;
    s[tid] = v;
    __syncthreads();
    for (int o = 1; o < 256; o <<= 1) {
        int t = (tid >= o) ? s[tid - o] : 0;
        __syncthreads();
        s[tid] += t;
        __syncthreads();
    }
    if (i < NN) rp[i] = s[tid] - v;     // exclusive, block-local
    if (tid == 255) part[blockIdx.x] = s[255];
}

__global__ __launch_bounds__(512) void scan2(int* __restrict__ part) {
    __shared__ int s[512];
    int tid = threadIdx.x;
    int v = (tid < NBLK) ? part[tid] : 0;
    s[tid] = v;
    __syncthreads();
    for (int o = 1; o < 512; o <<= 1) {
        int t = (tid >= o) ? s[tid - o] : 0;
        __syncthreads();
        s[tid] += t;
        __syncthreads();
    }
    if (tid < NBLK) part[tid] = s[tid] - v;   // exclusive over blocks
}

__global__ __launch_bounds__(256) void scan3(int* __restrict__ rp,
                                             const int* __restrict__ part,
                                             const int* __restrict__ deg,
                                             int* __restrict__ cnt) {
    int i = blockIdx.x * 256 + threadIdx.x;
    if (i < NN) {
        int val = rp[i] + part[i >> 8];
        rp[i] = val;
        cnt[i] = 0;
        if (i == NN - 1) rp[NN] = val + ((deg[i] + 15) & ~15);
    }
}

__global__ __launch_bounds__(256) void fill_csr(const int* __restrict__ ei,
                                                const int* __restrict__ rp,
                                                int* __restrict__ cnt,
                                                int* __restrict__ csr) {
    unsigned int e = blockIdx.x * 256u + threadIdx.x;   // < NE
    int s = ei[e];
    int d = ei[NE + e];
    int pos = atomicAdd(&cnt[d], 1);
    csr[rp[d] + pos] = s;
}

// ---------------- fused layer: gather-agg + MLP + BN ----------------
// 4 groups of 16 lanes per wave; each group loads full 256 B neighbor rows
// with uint4 (16 B/lane) loads, 4-deep; padded CSR -> no tail, no masks.
__global__ __launch_bounds__(256) void layer_fused(
    const unsigned short* __restrict__ hin,   // (NN+1) rows, row NN = zeros
    const int* __restrict__ rp,               // padded row ptr
    const int* __restrict__ csr,              // padded neighbor lists
    const unsigned short* __restrict__ w1t,   // [n][k] bf16
    const unsigned short* __restrict__ w2t,   // [n][k] bf16
    const float* __restrict__ b1,
    const float* __restrict__ b2,
    const float* __restrict__ gamma,
    const float* __restrict__ beta,
    const float* __restrict__ rmean,
    const float* __restrict__ rvar,
    const float* __restrict__ epsv,
    unsigned short* __restrict__ hout)
{
    __shared__ unsigned short z_lds[64 * 136];   // 17.4 KB only
    const int tid = threadIdx.x;
    const int lane = tid & 63;
    const int wave = tid >> 6;
    const int gid = lane >> 4;        // neighbor group 0..3
    const int lg = lane & 15;         // feature slice within group
    const int row0 = blockIdx.x * 64;
    const float epl = 1.0f + epsv[0];
    const size_t lgo = (size_t)lg * 8;

#define ACC8(v) do { \
    acc[0] += bflo((v).x); acc[1] += bfhi((v).x); \
    acc[2] += bflo((v).y); acc[3] += bfhi((v).y); \
    acc[4] += bflo((v).z); acc[5] += bfhi((v).z); \
    acc[6] += bflo((v).w); acc[7] += bfhi((v).w); } while (0)

    // Phase 1: gather-aggregate 16 rows per wave -> z tile bf16 in LDS
    for (int rr = 0; rr < 16; ++rr) {
        int r = (wave << 4) + rr;
        int gr = row0 + r;
        float acc[8];
        #pragma unroll
        for (int e = 0; e < 8; ++e) acc[e] = 0.f;
        if (gr < NN) {
            if (gid == 0) {
                uint4 sv = *reinterpret_cast<const uint4*>(hin + (size_t)gr * DD + lgo);
                acc[0] += epl * bflo(sv.x); acc[1] += epl * bfhi(sv.x);
                acc[2] += epl * bflo(sv.y); acc[3] += epl * bfhi(sv.y);
                acc[4] += epl * bflo(sv.z); acc[5] += epl * bfhi(sv.z);
                acc[6] += epl * bflo(sv.w); acc[7] += epl * bfhi(sv.w);
            }
            int st = rp[gr], en = rp[gr + 1];
            for (int c0 = st; c0 < en; c0 += 64) {
                int nc = en - c0; nc = nc < 64 ? nc : 64;   // multiple of 16
                int my = (lane < nc) ? csr[c0 + lane] : NN;
                for (int q0 = 0; q0 < nc; q0 += 16) {
                    int i0 = __shfl(my, q0 + gid);
                    int i1 = __shfl(my, q0 + 4 + gid);
                    int i2 = __shfl(my, q0 + 8 + gid);
                    int i3 = __shfl(my, q0 + 12 + gid);
                    uint4 v0 = *reinterpret_cast<const uint4*>(hin + (size_t)i0 * DD + lgo);
                    uint4 v1 = *reinterpret_cast<const uint4*>(hin + (size_t)i1 * DD + lgo);
                    uint4 v2 = *reinterpret_cast<const uint4*>(hin + (size_t)i2 * DD + lgo);
                    uint4 v3 = *reinterpret_cast<const uint4*>(hin + (size_t)i3 * DD + lgo);
                    ACC8(v0); ACC8(v1); ACC8(v2); ACC8(v3);
                }
            }
        }
        // cross-group reduce (sum over gid)
        #pragma unroll
        for (int e = 0; e < 8; ++e) {
            acc[e] += __shfl_xor(acc[e], 16);
            acc[e] += __shfl_xor(acc[e], 32);
        }
        if (gid == 0) {
            uint4 pk;
            pk.x = (unsigned)f2bf(acc[0]) | ((unsigned)f2bf(acc[1]) << 16);
            pk.y = (unsigned)f2bf(acc[2]) | ((unsigned)f2bf(acc[3]) << 16);
            pk.z = (unsigned)f2bf(acc[4]) | ((unsigned)f2bf(acc[5]) << 16);
            pk.w = (unsigned)f2bf(acc[6]) | ((unsigned)f2bf(acc[7]) << 16);
            *reinterpret_cast<uint4*>(&z_lds[r * 136 + lg * 8]) = pk;
        }
    }
    __syncthreads();

    const int l15 = lane & 15;
    const int kq = lane >> 4;
    const int arow = (wave << 4) + l15;

    // Matmul 1 (B-fragments straight from global; 32 KB weight is L1-hot)
    bf16x8 afr[4];
    #pragma unroll
    for (int kk = 0; kk < 4; ++kk)
        afr[kk] = *reinterpret_cast<const bf16x8*>(&z_lds[arow * 136 + kk * 32 + kq * 8]);

    f32x4 acc[8];
    #pragma unroll
    for (int nt = 0; nt < 8; ++nt) acc[nt] = (f32x4){0.f, 0.f, 0.f, 0.f};
    #pragma unroll
    for (int nt = 0; nt < 8; ++nt) {
        #pragma unroll
        for (int kk = 0; kk < 4; ++kk) {
            bf16x8 bfr = *reinterpret_cast<const bf16x8*>(
                w1t + (nt * 16 + l15) * DD + kk * 32 + kq * 8);
            acc[nt] = __builtin_amdgcn_mfma_f32_16x16x32_bf16(afr[kk], bfr, acc[nt], 0, 0, 0);
        }
    }

    // Epilogue 1: bias+relu, z1 -> z_lds (own wave's 16-row stripe only)
    #pragma unroll
    for (int nt = 0; nt < 8; ++nt) {
        int col = nt * 16 + l15;
        float bv = b1[col];
        #pragma unroll
        for (int r = 0; r < 4; ++r) {
            int zr = (wave << 4) + kq * 4 + r;
            float v = acc[nt][r] + bv;
            v = v > 0.f ? v : 0.f;
            z_lds[zr * 136 + col] = f2bf(v);
        }
    }
    __syncthreads();

    // Matmul 2
    #pragma unroll
    for (int kk = 0; kk < 4; ++kk)
        afr[kk] = *reinterpret_cast<const bf16x8*>(&z_lds[arow * 136 + kk * 32 + kq * 8]);
    #pragma unroll
    for (int nt = 0; nt < 8; ++nt) acc[nt] = (f32x4){0.f, 0.f, 0.f, 0.f};
    #pragma unroll
    for (int nt = 0; nt < 8; ++nt) {
        #pragma unroll
        for (int kk = 0; kk < 4; ++kk) {
            bf16x8 bfr = *reinterpret_cast<const bf16x8*>(
                w2t + (nt * 16 + l15) * DD + kk * 32 + kq * 8);
            acc[nt] = __builtin_amdgcn_mfma_f32_16x16x32_bf16(afr[kk], bfr, acc[nt], 0, 0, 0);
        }
    }

    // Epilogue 2: bias+relu+BN -> hout (bf16)
    #pragma unroll
    for (int nt = 0; nt < 8; ++nt) {
        int col = nt * 16 + l15;
        float bv = b2[col];
        float ga = gamma[col];
        float be = beta[col];
        float mu = rmean[col];
        float inv = rsqrtf(rvar[col] + 1e-5f);
        #pragma unroll
        for (int r = 0; r < 4; ++r) {
            int zr = (wave << 4) + kq * 4 + r;
            int gr = row0 + zr;
            if (gr < NN) {
                float v = acc[nt][r] + bv;
                v = v > 0.f ? v : 0.f;
                v = (v - mu) * inv * ga + be;
                hout[(size_t)gr * DD + col] = f2bf(v);
            }
        }
    }
#undef ACC8
}

// ---------------- pool (sorted batch -> segment sums) + final linear ----------------
__global__ __launch_bounds__(256) void pool_final(const unsigned short* __restrict__ h,
                                                  const int* __restrict__ batch,
                                                  const float* __restrict__ W,
                                                  const float* __restrict__ b,
                                                  float* __restrict__ out) {
    int g = blockIdx.x;           // one block per graph
    int t = threadIdx.x;          // 256 threads
    int c = t & 127;
    int half = t >> 7;

    int lo = 0, hi = NN;
    while (lo < hi) { int mid = (lo + hi) >> 1; if (batch[mid] < g) lo = mid + 1; else hi = mid; }
    int start = lo;
    hi = NN;
    while (lo < hi) { int mid = (lo + hi) >> 1; if (batch[mid] < g + 1) lo = mid + 1; else hi = mid; }
    int end = lo;

    float s = 0.f;
    for (int i = start + half; i < end; i += 2)
        s += bf2f(h[(size_t)i * DD + c]);

    __shared__ float ps[2][DD];
    ps[half][c] = s;
    __syncthreads();
    if (half == 0) {
        float cnt = (float)(end - start);
        float pooled = (ps[0][c] + ps[1][c]) / fmaxf(cnt, 1.0f);
        ps[0][c] = pooled;
    }
    __syncthreads();
    if (half == 0) {
        float o = b[c];
        #pragma unroll 8
        for (int k = 0; k < DD; ++k)
            o += ps[0][k] * W[k * DD + c];
        out[(size_t)g * DD + c] = fmaxf(o, 0.f);
    }
}

extern "C" void kernel_launch(void* const* d_in, const int* in_sizes, int n_in,
                              void* d_out, int out_size, void* d_ws, size_t ws_size,
                              hipStream_t stream) {
    const float* x     = (const float*)d_in[0];
    const int*   ei    = (const int*)d_in[1];
    const int*   batch = (const int*)d_in[2];
    const float* W1    = (const float*)d_in[3];
    const float* b1    = (const float*)d_in[4];
    const float* W2    = (const float*)d_in[5];
    const float* b2    = (const float*)d_in[6];
    const float* gamma = (const float*)d_in[7];
    const float* beta  = (const float*)d_in[8];
    const float* rmean = (const float*)d_in[9];
    const float* rvar  = (const float*)d_in[10];
    const float* eps   = (const float*)d_in[11];
    const float* lin1W = (const float*)d_in[12];
    const float* lin1b = (const float*)d_in[13];
    float* out = (float*)d_out;

    char* ws = (char*)d_ws;
    size_t off = 0;
    auto alloc = [&](size_t bytes) {
        void* p = ws + off;
        off = (off + bytes + 255) & ~(size_t)255;
        return p;
    };
    unsigned short* h0  = (unsigned short*)alloc((size_t)(NN + 1) * DD * 2);
    unsigned short* h1  = (unsigned short*)alloc((size_t)(NN + 1) * DD * 2);
    int* rp   = (int*)alloc((size_t)(NN + 1) * 4);
    int* deg  = (int*)alloc((size_t)NN * 4);
    int* cnt  = (int*)alloc((size_t)NN * 4);
    int* part = (int*)alloc(512 * 4);
    int* csr  = (int*)alloc((size_t)CSRP * 4);
    unsigned short* wbf = (unsigned short*)alloc((size_t)NL * 2 * DD * DD * 2);

    prep_w<<<NL * 2 * DD * DD / 256, 256, 0, stream>>>(W1, W2, wbf);
    conv_x<<<(int)(((long long)(NN + 1) * DD / 4 + 255) / 256), 256, 0, stream>>>(x, h0, h1);

    // CSR build (edge structure is layer-invariant), padded to 16 w/ dummy NN
    hipMemsetAsync(deg, 0, (size_t)NN * 4, stream);
    hist_deg<<<NE / 256, 256, 0, stream>>>(ei, deg);
    scan1<<<NBLK, 256, 0, stream>>>(deg, rp, part);
    scan2<<<1, 512, 0, stream>>>(part);
    scan3<<<NBLK, 256, 0, stream>>>(rp, part, deg, cnt);
    fill_pad<<<CSRP / 4 / 256, 256, 0, stream>>>(csr);
    fill_csr<<<NE / 256, 256, 0, stream>>>(ei, rp, cnt, csr);

    const int lgrid = (NN + 63) / 64;
    // L0: h0 -> h1 ; L1: h1 -> h0 ; L2: h0 -> h1
    layer_fused<<<lgrid, 256, 0, stream>>>(
        h0, rp, csr, wbf + 0 * DD * DD, wbf + 1 * DD * DD,
        b1 + 0 * DD, b2 + 0 * DD, gamma + 0 * DD, beta + 0 * DD,
        rmean + 0 * DD, rvar + 0 * DD, eps + 0, h1);
    layer_fused<<<lgrid, 256, 0, stream>>>(
        h1, rp, csr, wbf + 2 * DD * DD, wbf + 3 * DD * DD,
        b1 + 1 * DD, b2 + 1 * DD, gamma + 1 * DD, beta + 1 * DD,
        rmean + 1 * DD, rvar + 1 * DD, eps + 1, h0);
    layer_fused<<<lgrid, 256, 0, stream>>>(
        h0, rp, csr, wbf + 4 * DD * DD, wbf + 5 * DD * DD,
        b1 + 2 * DD, b2 + 2 * DD, gamma + 2 * DD, beta + 2 * DD,
        rmean + 2 * DD, rvar + 2 * DD, eps + 2, h1);

    pool_final<<<NG, 256, 0, stream>>>(h1, batch, lin1W, lin1b, out);
}

// Round 5
// 633.745 us; speedup vs baseline: 13.5829x; 1.1507x over previous
//
#include <hip/hip_runtime.h>
#include <hip/hip_bf16.h>

#define NN 100000
#define NE 1600000
#define DD 128
#define NL 3
#define NG 512
#define NBLK ((NN + 255) / 256)        // 391 scan blocks
#define CSRP (NE + 16 * NN)            // padded CSR capacity (ints) = 3.2M

// fused init kernel block ranges (256 threads each)
#define CONV_BLKS 12501                // (NN+1)*DD/4 threads
#define PAD_BLKS  3125                 // CSRP/4 threads
#define PREPW_BLKS 384                 // NL*2*DD*DD/256
#define DEG_BLKS  391                  // NN/256
#define INIT_BLKS (CONV_BLKS + PAD_BLKS + PREPW_BLKS + DEG_BLKS)

typedef __attribute__((ext_vector_type(8))) short bf16x8;
typedef __attribute__((ext_vector_type(4))) float f32x4;

__device__ __forceinline__ unsigned short f2bf(float f) {
    union { float f; unsigned int u; } x; x.f = f;
    unsigned int r = x.u + 0x7FFFu + ((x.u >> 16) & 1u);
    return (unsigned short)(r >> 16);
}
__device__ __forceinline__ float bf2f(unsigned short u) {
    union { unsigned int u; float f; } x; x.u = ((unsigned int)u) << 16;
    return x.f;
}
__device__ __forceinline__ float bflo(unsigned int v) { return bf2f((unsigned short)(v & 0xffffu)); }
__device__ __forceinline__ float bfhi(unsigned int v) { return bf2f((unsigned short)(v >> 16)); }
__device__ __forceinline__ unsigned cvtpk(float lo, float hi) {
    unsigned r;
    asm("v_cvt_pk_bf16_f32 %0, %1, %2" : "=v"(r) : "v"(lo), "v"(hi));
    return r;
}

// -------- fused init: conv_x | fill_pad | prep_w | deg=0 --------
__global__ __launch_bounds__(256) void init_all(const float* __restrict__ x,
                                                unsigned short* __restrict__ h0,
                                                unsigned short* __restrict__ h1,
                                                int* __restrict__ csr,
                                                const float* __restrict__ W1,
                                                const float* __restrict__ W2,
                                                unsigned short* __restrict__ wbf,
                                                int* __restrict__ deg) {
    int bb = blockIdx.x;
    if (bb < CONV_BLKS) {
        long long t = (long long)bb * 256 + threadIdx.x;
        long long base = t * 4;
        if (base < (long long)NN * DD) {
            float4 v = *reinterpret_cast<const float4*>(x + base);
            ushort4 p;
            p.x = f2bf(v.x); p.y = f2bf(v.y); p.z = f2bf(v.z); p.w = f2bf(v.w);
            *reinterpret_cast<ushort4*>(h0 + base) = p;
        } else if (base < (long long)(NN + 1) * DD) {
            ushort4 z = {0, 0, 0, 0};
            *reinterpret_cast<ushort4*>(h0 + base) = z;
            *reinterpret_cast<ushort4*>(h1 + base) = z;
        }
        return;
    }
    bb -= CONV_BLKS;
    if (bb < PAD_BLKS) {
        size_t t = (size_t)bb * 256 + threadIdx.x;   // < CSRP/4
        int4 v = {NN, NN, NN, NN};
        *reinterpret_cast<int4*>(csr + t * 4) = v;
        return;
    }
    bb -= PAD_BLKS;
    if (bb < PREPW_BLKS) {
        int idx = bb * 256 + threadIdx.x;            // < NL*2*DD*DD
        int k = idx & 127;
        int n = (idx >> 7) & 127;
        int w = (idx >> 14) & 1;
        int l = idx >> 15;
        const float* src = w ? W2 : W1;
        wbf[idx] = f2bf(src[(l * DD + k) * DD + n]);
        return;
    }
    bb -= PREPW_BLKS;
    int i = bb * 256 + threadIdx.x;
    if (i < NN) deg[i] = 0;
}

// ---------------- CSR build (once per call) ----------------
__global__ __launch_bounds__(256) void hist_deg(const int* __restrict__ ei,
                                                int* __restrict__ deg) {
    unsigned int e = blockIdx.x * 256u + threadIdx.x;   // < NE
    atomicAdd(&deg[ei[NE + e]], 1);
}

// scan over PADDED degrees: pdeg = ceil(deg/16)*16
__global__ __launch_bounds__(256) void scan1(const int* __restrict__ deg,
                                             int* __restrict__ rp,
                                             int* __restrict__ part) {
    __shared__ int s[256];
    int tid = threadIdx.x;
    int i = blockIdx.x * 256 + tid;
    int v = 0;
    if (i < NN) v = (deg[i] + 15) & ~15;
    s[tid] = v;
    __syncthreads();
    for (int o = 1; o < 256; o <<= 1) {
        int t = (tid >= o) ? s[tid - o] : 0;
        __syncthreads();
        s[tid] += t;
        __syncthreads();
    }
    if (i < NN) rp[i] = s[tid] - v;
    if (tid == 255) part[blockIdx.x] = s[255];
}

__global__ __launch_bounds__(512) void scan2(int* __restrict__ part) {
    __shared__ int s[512];
    int tid = threadIdx.x;
    int v = (tid < NBLK) ? part[tid] : 0;
    s[tid] = v;
    __syncthreads();
    for (int o = 1; o < 512; o <<= 1) {
        int t = (tid >= o) ? s[tid - o] : 0;
        __syncthreads();
        s[tid] += t;
        __syncthreads();
    }
    if (tid < NBLK) part[tid] = s[tid] - v;
}

__global__ __launch_bounds__(256) void scan3(int* __restrict__ rp,
                                             const int* __restrict__ part,
                                             const int* __restrict__ deg,
                                             int* __restrict__ cnt) {
    int i = blockIdx.x * 256 + threadIdx.x;
    if (i < NN) {
        int val = rp[i] + part[i >> 8];
        rp[i] = val;
        cnt[i] = 0;
        if (i == NN - 1) rp[NN] = val + ((deg[i] + 15) & ~15);
    }
}

__global__ __launch_bounds__(256) void fill_csr(const int* __restrict__ ei,
                                                const int* __restrict__ rp,
                                                int* __restrict__ cnt,
                                                int* __restrict__ csr) {
    unsigned int e = blockIdx.x * 256u + threadIdx.x;   // < NE
    int s = ei[e];
    int d = ei[NE + e];
    int pos = atomicAdd(&cnt[d], 1);
    csr[rp[d] + pos] = s;
}

// ---------------- fused layer: gather-agg + MLP + BN ----------------
// 32 rows/block (NN = 3125*32 exactly, no tail). 4 waves:
//  gather: wave w owns rows w*8..w*8+7; 16-lane groups load whole 256B rows.
//  MFMA:   wave w -> row-tile (w&1), col-half (w>>1); 16 MFMAs per matmul.
__global__ __launch_bounds__(256) void layer_fused(
    const unsigned short* __restrict__ hin,   // (NN+1) rows, row NN = zeros
    const int* __restrict__ rp,               // padded row ptr (16-aligned)
    const int* __restrict__ csr,              // padded neighbor lists
    const unsigned short* __restrict__ w1t,   // [n][k] bf16
    const unsigned short* __restrict__ w2t,   // [n][k] bf16
    const float* __restrict__ b1,
    const float* __restrict__ b2,
    const float* __restrict__ gamma,
    const float* __restrict__ beta,
    const float* __restrict__ rmean,
    const float* __restrict__ rvar,
    const float* __restrict__ epsv,
    unsigned short* __restrict__ hout)
{
    __shared__ unsigned short z_lds[32 * 136];   // 8.7 KB
    const int tid = threadIdx.x;
    const int lane = tid & 63;
    const int wave = tid >> 6;
    const int gid = lane >> 4;        // neighbor group 0..3
    const int lg = lane & 15;         // 16B feature slice within group
    const int row0 = blockIdx.x * 32;
    const float epl = 1.0f + epsv[0];
    const size_t lgo = (size_t)lg * 8;

#define ACC8(v) do { \
    acc[0] += bflo((v).x); acc[1] += bfhi((v).x); \
    acc[2] += bflo((v).y); acc[3] += bfhi((v).y); \
    acc[4] += bflo((v).z); acc[5] += bfhi((v).z); \
    acc[6] += bflo((v).w); acc[7] += bfhi((v).w); } while (0)

    // Phase 1: gather-aggregate 8 rows per wave -> z tile bf16 in LDS
    const int rbase = row0 + (wave << 3);
    int pv = (lane < 9) ? rp[rbase + lane] : 0;   // prefetch 9 rowptrs

    for (int rr = 0; rr < 8; ++rr) {
        int gr = rbase + rr;
        int st = __shfl(pv, rr);
        int en = __shfl(pv, rr + 1);
        float acc[8];
        if (gid == 0) {
            uint4 sv = *reinterpret_cast<const uint4*>(hin + (size_t)gr * DD + lgo);
            acc[0] = epl * bflo(sv.x); acc[1] = epl * bfhi(sv.x);
            acc[2] = epl * bflo(sv.y); acc[3] = epl * bfhi(sv.y);
            acc[4] = epl * bflo(sv.z); acc[5] = epl * bfhi(sv.z);
            acc[6] = epl * bflo(sv.w); acc[7] = epl * bfhi(sv.w);
        } else {
            #pragma unroll
            for (int e = 0; e < 8; ++e) acc[e] = 0.f;
        }
        for (int c0 = st; c0 < en; c0 += 16) {
            // each 16-lane group broadcasts 4 neighbor ids with one int4 load
            int4 id4 = *reinterpret_cast<const int4*>(csr + c0 + (gid << 2));
            uint4 v0 = *reinterpret_cast<const uint4*>(hin + (size_t)id4.x * DD + lgo);
            uint4 v1 = *reinterpret_cast<const uint4*>(hin + (size_t)id4.y * DD + lgo);
            uint4 v2 = *reinterpret_cast<const uint4*>(hin + (size_t)id4.z * DD + lgo);
            uint4 v3 = *reinterpret_cast<const uint4*>(hin + (size_t)id4.w * DD + lgo);
            ACC8(v0); ACC8(v1); ACC8(v2); ACC8(v3);
        }
        #pragma unroll
        for (int e = 0; e < 8; ++e) {
            acc[e] += __shfl_xor(acc[e], 16);
            acc[e] += __shfl_xor(acc[e], 32);
        }
        if (gid == 0) {
            uint4 pk;
            pk.x = cvtpk(acc[0], acc[1]);
            pk.y = cvtpk(acc[2], acc[3]);
            pk.z = cvtpk(acc[4], acc[5]);
            pk.w = cvtpk(acc[6], acc[7]);
            *reinterpret_cast<uint4*>(&z_lds[((wave << 3) + rr) * 136 + lg * 8]) = pk;
        }
    }
    __syncthreads();

    const int l15 = lane & 15;
    const int kq = lane >> 4;
    const int t16 = wave & 1;          // row-tile 0..1
    const int nh = wave >> 1;          // col-half 0..1
    const int arow = (t16 << 4) + l15;

    // Matmul 1 (B-fragments straight from global; 32 KB weight is L1-hot)
    bf16x8 afr[4];
    #pragma unroll
    for (int kk = 0; kk < 4; ++kk)
        afr[kk] = *reinterpret_cast<const bf16x8*>(&z_lds[arow * 136 + kk * 32 + kq * 8]);

    f32x4 acc4[4];
    #pragma unroll
    for (int nt = 0; nt < 4; ++nt) acc4[nt] = (f32x4){0.f, 0.f, 0.f, 0.f};
    #pragma unroll
    for (int nt = 0; nt < 4; ++nt) {
        #pragma unroll
        for (int kk = 0; kk < 4; ++kk) {
            bf16x8 bfr = *reinterpret_cast<const bf16x8*>(
                w1t + ((nh * 4 + nt) * 16 + l15) * DD + kk * 32 + kq * 8);
            acc4[nt] = __builtin_amdgcn_mfma_f32_16x16x32_bf16(afr[kk], bfr, acc4[nt], 0, 0, 0);
        }
    }
    __syncthreads();   // all afr reads done before epi1 writes (tile shared by 2 waves)

    // Epilogue 1: bias+relu, z1 -> z_lds
    #pragma unroll
    for (int nt = 0; nt < 4; ++nt) {
        int col = (nh * 4 + nt) * 16 + l15;
        float bv = b1[col];
        #pragma unroll
        for (int r = 0; r < 4; ++r) {
            int zr = (t16 << 4) + kq * 4 + r;
            float v = acc4[nt][r] + bv;
            v = v > 0.f ? v : 0.f;
            z_lds[zr * 136 + col] = f2bf(v);
        }
    }
    __syncthreads();

    // Matmul 2
    #pragma unroll
    for (int kk = 0; kk < 4; ++kk)
        afr[kk] = *reinterpret_cast<const bf16x8*>(&z_lds[arow * 136 + kk * 32 + kq * 8]);
    #pragma unroll
    for (int nt = 0; nt < 4; ++nt) acc4[nt] = (f32x4){0.f, 0.f, 0.f, 0.f};
    #pragma unroll
    for (int nt = 0; nt < 4; ++nt) {
        #pragma unroll
        for (int kk = 0; kk < 4; ++kk) {
            bf16x8 bfr = *reinterpret_cast<const bf16x8*>(
                w2t + ((nh * 4 + nt) * 16 + l15) * DD + kk * 32 + kq * 8);
            acc4[nt] = __builtin_amdgcn_mfma_f32_16x16x32_bf16(afr[kk], bfr, acc4[nt], 0, 0, 0);
        }
    }

    // Epilogue 2: bias+relu+BN -> hout (bf16); rows always < NN (no tail)
    #pragma unroll
    for (int nt = 0; nt < 4; ++nt) {
        int col = (nh * 4 + nt) * 16 + l15;
        float bv = b2[col];
        float ga = gamma[col];
        float be = beta[col];
        float mu = rmean[col];
        float inv = rsqrtf(rvar[col] + 1e-5f);
        #pragma unroll
        for (int r = 0; r < 4; ++r) {
            int zr = (t16 << 4) + kq * 4 + r;
            float v = acc4[nt][r] + bv;
            v = v > 0.f ? v : 0.f;
            v = (v - mu) * inv * ga + be;
            hout[(size_t)(row0 + zr) * DD + col] = f2bf(v);
        }
    }
#undef ACC8
}

// ---------------- pool (sorted batch -> segment sums) + final linear ----------------
__global__ __launch_bounds__(256) void pool_final(const unsigned short* __restrict__ h,
                                                  const int* __restrict__ batch,
                                                  const float* __restrict__ W,
                                                  const float* __restrict__ b,
                                                  float* __restrict__ out) {
    int g = blockIdx.x;           // one block per graph
    int t = threadIdx.x;
    int c2 = t & 63;              // col pair 2*c2, 2*c2+1
    int qu = t >> 6;              // row strand 0..3

    int lo = 0, hi = NN;
    while (lo < hi) { int mid = (lo + hi) >> 1; if (batch[mid] < g) lo = mid + 1; else hi = mid; }
    int start = lo;
    hi = NN;
    while (lo < hi) { int mid = (lo + hi) >> 1; if (batch[mid] < g + 1) lo = mid + 1; else hi = mid; }
    int end = lo;

    float ax = 0.f, ay = 0.f;
    for (int i = start + qu; i < end; i += 4) {
        unsigned u = *reinterpret_cast<const unsigned*>(h + (size_t)i * DD + c2 * 2);
        ax += bflo(u); ay += bfhi(u);
    }

    __shared__ float ps[4][DD];
    ps[qu][c2 * 2] = ax;
    ps[qu][c2 * 2 + 1] = ay;
    __syncthreads();
    if (t < DD) {
        float inv = 1.0f / fmaxf((float)(end - start), 1.0f);
        ps[0][t] = (ps[0][t] + ps[1][t] + ps[2][t] + ps[3][t]) * inv;
    }
    __syncthreads();
    if (t < DD) {
        float o = b[t];
        #pragma unroll 8
        for (int k = 0; k < DD; ++k)
            o += ps[0][k] * W[k * DD + t];
        out[(size_t)g * DD + t] = fmaxf(o, 0.f);
    }
}

extern "C" void kernel_launch(void* const* d_in, const int* in_sizes, int n_in,
                              void* d_out, int out_size, void* d_ws, size_t ws_size,
                              hipStream_t stream) {
    const float* x     = (const float*)d_in[0];
    const int*   ei    = (const int*)d_in[1];
    const int*   batch = (const int*)d_in[2];
    const float* W1    = (const float*)d_in[3];
    const float* b1    = (const float*)d_in[4];
    const float* W2    = (const float*)d_in[5];
    const float* b2    = (const float*)d_in[6];
    const float* gamma = (const float*)d_in[7];
    const float* beta  = (const float*)d_in[8];
    const float* rmean = (const float*)d_in[9];
    const float* rvar  = (const float*)d_in[10];
    const float* eps   = (const float*)d_in[11];
    const float* lin1W = (const float*)d_in[12];
    const float* lin1b = (const float*)d_in[13];
    float* out = (float*)d_out;

    char* ws = (char*)d_ws;
    size_t off = 0;
    auto alloc = [&](size_t bytes) {
        void* p = ws + off;
        off = (off + bytes + 255) & ~(size_t)255;
        return p;
    };
    unsigned short* h0  = (unsigned short*)alloc((size_t)(NN + 1) * DD * 2);
    unsigned short* h1  = (unsigned short*)alloc((size_t)(NN + 1) * DD * 2);
    int* rp   = (int*)alloc((size_t)(NN + 1) * 4);
    int* deg  = (int*)alloc((size_t)NN * 4);
    int* cnt  = (int*)alloc((size_t)NN * 4);
    int* part = (int*)alloc(512 * 4);
    int* csr  = (int*)alloc((size_t)CSRP * 4);
    unsigned short* wbf = (unsigned short*)alloc((size_t)NL * 2 * DD * DD * 2);

    init_all<<<INIT_BLKS, 256, 0, stream>>>(x, h0, h1, csr, W1, W2, wbf, deg);

    hist_deg<<<NE / 256, 256, 0, stream>>>(ei, deg);
    scan1<<<NBLK, 256, 0, stream>>>(deg, rp, part);
    scan2<<<1, 512, 0, stream>>>(part);
    scan3<<<NBLK, 256, 0, stream>>>(rp, part, deg, cnt);
    fill_csr<<<NE / 256, 256, 0, stream>>>(ei, rp, cnt, csr);

    const int lgrid = NN / 32;   // 3125, exact
    layer_fused<<<lgrid, 256, 0, stream>>>(
        h0, rp, csr, wbf + 0 * DD * DD, wbf + 1 * DD * DD,
        b1 + 0 * DD, b2 + 0 * DD, gamma + 0 * DD, beta + 0 * DD,
        rmean + 0 * DD, rvar + 0 * DD, eps + 0, h1);
    layer_fused<<<lgrid, 256, 0, stream>>>(
        h1, rp, csr, wbf + 2 * DD * DD, wbf + 3 * DD * DD,
        b1 + 1 * DD, b2 + 1 * DD, gamma + 1 * DD, beta + 1 * DD,
        rmean + 1 * DD, rvar + 1 * DD, eps + 1, h0);
    layer_fused<<<lgrid, 256, 0, stream>>>(
        h0, rp, csr, wbf + 4 * DD * DD, wbf + 5 * DD * DD,
        b1 + 2 * DD, b2 + 2 * DD, gamma + 2 * DD, beta + 2 * DD,
        rmean + 2 * DD, rvar + 2 * DD, eps + 2, h1);

    pool_final<<<NG, 256, 0, stream>>>(h1, batch, lin1W, lin1b, out);
}

// Round 6
// 611.668 us; speedup vs baseline: 14.0732x; 1.0361x over previous
//
#include <hip/hip_runtime.h>
#include <hip/hip_bf16.h>

#define NN 100000
#define NE 1600000
#define DD 128
#define NL 3
#define NG 512
#define NBLK ((NN + 255) / 256)        // 391 scan blocks
#define CSRP (NE + 16 * NN)            // padded CSR capacity (ints) = 3.2M

// fused init kernel block ranges (256 threads each)
#define CONV_BLKS 12501                // (NN+1)*DD/4 threads
#define PREPW_BLKS 384                 // NL*2*DD*DD/256
#define DEG_BLKS  391                  // NN/256
#define INIT_BLKS (CONV_BLKS + PREPW_BLKS + DEG_BLKS)

typedef __attribute__((ext_vector_type(8))) short bf16x8;
typedef __attribute__((ext_vector_type(4))) float f32x4;

__device__ __forceinline__ unsigned short f2bf(float f) {
    union { float f; unsigned int u; } x; x.f = f;
    unsigned int r = x.u + 0x7FFFu + ((x.u >> 16) & 1u);
    return (unsigned short)(r >> 16);
}
__device__ __forceinline__ float bf2f(unsigned short u) {
    union { unsigned int u; float f; } x; x.u = ((unsigned int)u) << 16;
    return x.f;
}
__device__ __forceinline__ float bflo(unsigned int v) { return bf2f((unsigned short)(v & 0xffffu)); }
__device__ __forceinline__ float bfhi(unsigned int v) { return bf2f((unsigned short)(v >> 16)); }
__device__ __forceinline__ unsigned cvtpk(float lo, float hi) {
    unsigned r;
    asm("v_cvt_pk_bf16_f32 %0, %1, %2" : "=v"(r) : "v"(lo), "v"(hi));
    return r;
}

// -------- fused init: conv_x | prep_w | deg=0 --------
__global__ __launch_bounds__(256) void init_all(const float* __restrict__ x,
                                                unsigned short* __restrict__ h0,
                                                unsigned short* __restrict__ h1,
                                                const float* __restrict__ W1,
                                                const float* __restrict__ W2,
                                                unsigned short* __restrict__ wbf,
                                                int* __restrict__ deg) {
    int bb = blockIdx.x;
    if (bb < CONV_BLKS) {
        long long t = (long long)bb * 256 + threadIdx.x;
        long long base = t * 4;
        if (base < (long long)NN * DD) {
            float4 v = *reinterpret_cast<const float4*>(x + base);
            ushort4 p;
            p.x = f2bf(v.x); p.y = f2bf(v.y); p.z = f2bf(v.z); p.w = f2bf(v.w);
            *reinterpret_cast<ushort4*>(h0 + base) = p;
        } else if (base < (long long)(NN + 1) * DD) {
            ushort4 z = {0, 0, 0, 0};
            *reinterpret_cast<ushort4*>(h0 + base) = z;
            *reinterpret_cast<ushort4*>(h1 + base) = z;
        }
        return;
    }
    bb -= CONV_BLKS;
    if (bb < PREPW_BLKS) {
        int idx = bb * 256 + threadIdx.x;            // < NL*2*DD*DD
        int k = idx & 127;
        int n = (idx >> 7) & 127;
        int w = (idx >> 14) & 1;
        int l = idx >> 15;
        const float* src = w ? W2 : W1;
        wbf[idx] = f2bf(src[(l * DD + k) * DD + n]);
        return;
    }
    bb -= PREPW_BLKS;
    int i = bb * 256 + threadIdx.x;
    if (i < NN) deg[i] = 0;
}

// ---------------- CSR build (once per call) ----------------
__global__ __launch_bounds__(256) void hist_deg(const int* __restrict__ ei,
                                                int* __restrict__ deg) {
    unsigned int e = blockIdx.x * 256u + threadIdx.x;   // < NE
    atomicAdd(&deg[ei[NE + e]], 1);
}

// scan over PADDED degrees: pdeg = ceil(deg/16)*16
__global__ __launch_bounds__(256) void scan1(const int* __restrict__ deg,
                                             int* __restrict__ rp,
                                             int* __restrict__ part) {
    __shared__ int s[256];
    int tid = threadIdx.x;
    int i = blockIdx.x * 256 + tid;
    int v = 0;
    if (i < NN) v = (deg[i] + 15) & ~15;
    s[tid] = v;
    __syncthreads();
    for (int o = 1; o < 256; o <<= 1) {
        int t = (tid >= o) ? s[tid - o] : 0;
        __syncthreads();
        s[tid] += t;
        __syncthreads();
    }
    if (i < NN) rp[i] = s[tid] - v;
    if (tid == 255) part[blockIdx.x] = s[255];
}

__global__ __launch_bounds__(512) void scan2(int* __restrict__ part) {
    __shared__ int s[512];
    int tid = threadIdx.x;
    int v = (tid < NBLK) ? part[tid] : 0;
    s[tid] = v;
    __syncthreads();
    for (int o = 1; o < 512; o <<= 1) {
        int t = (tid >= o) ? s[tid - o] : 0;
        __syncthreads();
        s[tid] += t;
        __syncthreads();
    }
    if (tid < NBLK) part[tid] = s[tid] - v;
}

// finalize rp, zero cnt, and write ONLY the pad slots (deg..pdeg) with NN
__global__ __launch_bounds__(256) void scan3(int* __restrict__ rp,
                                             const int* __restrict__ part,
                                             const int* __restrict__ deg,
                                             int* __restrict__ cnt,
                                             int* __restrict__ csr) {
    int i = blockIdx.x * 256 + threadIdx.x;
    if (i < NN) {
        int val = rp[i] + part[i >> 8];
        rp[i] = val;
        cnt[i] = 0;
        int d = deg[i];
        int pd = (d + 15) & ~15;
        for (int j = val + d; j < val + pd; ++j) csr[j] = NN;
        if (i == NN - 1) rp[NN] = val + pd;
    }
}

__global__ __launch_bounds__(256) void fill_csr(const int* __restrict__ ei,
                                                const int* __restrict__ rp,
                                                int* __restrict__ cnt,
                                                int* __restrict__ csr) {
    unsigned int e = blockIdx.x * 256u + threadIdx.x;   // < NE
    int s = ei[e];
    int d = ei[NE + e];
    int pos = atomicAdd(&cnt[d], 1);
    csr[rp[d] + pos] = s;
}

// ---------------- fused layer: gather-agg + MLP + BN ----------------
// 16 rows/block (NN = 6250*16 exactly, no tail). 4 waves:
//  gather: wave w owns rows w*4..w*4+3; 16-lane groups load whole 256B rows.
//  MFMA:   wave w -> 32-col slice of the 16x128 tile; 8 MFMAs per matmul.
__global__ __launch_bounds__(256) void layer_fused(
    const unsigned short* __restrict__ hin,   // (NN+1) rows, row NN = zeros
    const int* __restrict__ rp,               // padded row ptr (16-aligned)
    const int* __restrict__ csr,              // padded neighbor lists
    const unsigned short* __restrict__ w1t,   // [n][k] bf16
    const unsigned short* __restrict__ w2t,   // [n][k] bf16
    const float* __restrict__ b1,
    const float* __restrict__ b2,
    const float* __restrict__ gamma,
    const float* __restrict__ beta,
    const float* __restrict__ rmean,
    const float* __restrict__ rvar,
    const float* __restrict__ epsv,
    unsigned short* __restrict__ hout)
{
    __shared__ unsigned short z_lds[16 * 136];   // 4.35 KB
    const int tid = threadIdx.x;
    const int lane = tid & 63;
    const int wave = tid >> 6;
    const int gid = lane >> 4;        // neighbor group 0..3
    const int lg = lane & 15;         // 16B feature slice within group
    const int row0 = blockIdx.x * 16;
    const float epl = 1.0f + epsv[0];
    const size_t lgo = (size_t)lg * 8;

#define ACC8(v) do { \
    acc[0] += bflo((v).x); acc[1] += bfhi((v).x); \
    acc[2] += bflo((v).y); acc[3] += bfhi((v).y); \
    acc[4] += bflo((v).z); acc[5] += bfhi((v).z); \
    acc[6] += bflo((v).w); acc[7] += bfhi((v).w); } while (0)

    // Phase 1: gather-aggregate 4 rows per wave -> z tile bf16 in LDS
    const int rbase = row0 + (wave << 2);
    int pv = (lane < 5) ? rp[rbase + lane] : 0;   // prefetch 5 rowptrs

    for (int rr = 0; rr < 4; ++rr) {
        int gr = rbase + rr;
        int st = __shfl(pv, rr);
        int en = __shfl(pv, rr + 1);
        float acc[8];
        if (gid == 0) {
            uint4 sv = *reinterpret_cast<const uint4*>(hin + (size_t)gr * DD + lgo);
            acc[0] = epl * bflo(sv.x); acc[1] = epl * bfhi(sv.x);
            acc[2] = epl * bflo(sv.y); acc[3] = epl * bfhi(sv.y);
            acc[4] = epl * bflo(sv.z); acc[5] = epl * bfhi(sv.z);
            acc[6] = epl * bflo(sv.w); acc[7] = epl * bfhi(sv.w);
        } else {
            #pragma unroll
            for (int e = 0; e < 8; ++e) acc[e] = 0.f;
        }
        for (int c0 = st; c0 < en; c0 += 16) {
            // each 16-lane group broadcasts 4 neighbor ids with one int4 load
            int4 id4 = *reinterpret_cast<const int4*>(csr + c0 + (gid << 2));
            uint4 v0 = *reinterpret_cast<const uint4*>(hin + (size_t)id4.x * DD + lgo);
            uint4 v1 = *reinterpret_cast<const uint4*>(hin + (size_t)id4.y * DD + lgo);
            uint4 v2 = *reinterpret_cast<const uint4*>(hin + (size_t)id4.z * DD + lgo);
            uint4 v3 = *reinterpret_cast<const uint4*>(hin + (size_t)id4.w * DD + lgo);
            ACC8(v0); ACC8(v1); ACC8(v2); ACC8(v3);
        }
        #pragma unroll
        for (int e = 0; e < 8; ++e) {
            acc[e] += __shfl_xor(acc[e], 16);
            acc[e] += __shfl_xor(acc[e], 32);
        }
        if (gid == 0) {
            uint4 pk;
            pk.x = cvtpk(acc[0], acc[1]);
            pk.y = cvtpk(acc[2], acc[3]);
            pk.z = cvtpk(acc[4], acc[5]);
            pk.w = cvtpk(acc[6], acc[7]);
            *reinterpret_cast<uint4*>(&z_lds[((wave << 2) + rr) * 136 + lg * 8]) = pk;
        }
    }
    __syncthreads();

    const int l15 = lane & 15;
    const int kq = lane >> 4;
    const int colbase = wave << 5;     // 32-col slice per wave

    // Matmul 1 (B-fragments straight from global; 32 KB weight is L1/L2-hot)
    bf16x8 afr[4];
    #pragma unroll
    for (int kk = 0; kk < 4; ++kk)
        afr[kk] = *reinterpret_cast<const bf16x8*>(&z_lds[l15 * 136 + kk * 32 + kq * 8]);

    f32x4 acc4[2];
    #pragma unroll
    for (int nt = 0; nt < 2; ++nt) acc4[nt] = (f32x4){0.f, 0.f, 0.f, 0.f};
    #pragma unroll
    for (int nt = 0; nt < 2; ++nt) {
        #pragma unroll
        for (int kk = 0; kk < 4; ++kk) {
            bf16x8 bfr = *reinterpret_cast<const bf16x8*>(
                w1t + (colbase + nt * 16 + l15) * DD + kk * 32 + kq * 8);
            acc4[nt] = __builtin_amdgcn_mfma_f32_16x16x32_bf16(afr[kk], bfr, acc4[nt], 0, 0, 0);
        }
    }
    __syncthreads();   // all afr reads done before epi1 writes (tile shared by all waves)

    // Epilogue 1: bias+relu, z1 -> z_lds (own 32-col slice, rows 0..15)
    #pragma unroll
    for (int nt = 0; nt < 2; ++nt) {
        int col = colbase + nt * 16 + l15;
        float bv = b1[col];
        #pragma unroll
        for (int r = 0; r < 4; ++r) {
            int zr = kq * 4 + r;
            float v = acc4[nt][r] + bv;
            v = v > 0.f ? v : 0.f;
            z_lds[zr * 136 + col] = f2bf(v);
        }
    }
    __syncthreads();

    // Matmul 2
    #pragma unroll
    for (int kk = 0; kk < 4; ++kk)
        afr[kk] = *reinterpret_cast<const bf16x8*>(&z_lds[l15 * 136 + kk * 32 + kq * 8]);
    #pragma unroll
    for (int nt = 0; nt < 2; ++nt) acc4[nt] = (f32x4){0.f, 0.f, 0.f, 0.f};
    #pragma unroll
    for (int nt = 0; nt < 2; ++nt) {
        #pragma unroll
        for (int kk = 0; kk < 4; ++kk) {
            bf16x8 bfr = *reinterpret_cast<const bf16x8*>(
                w2t + (colbase + nt * 16 + l15) * DD + kk * 32 + kq * 8);
            acc4[nt] = __builtin_amdgcn_mfma_f32_16x16x32_bf16(afr[kk], bfr, acc4[nt], 0, 0, 0);
        }
    }

    // Epilogue 2: bias+relu+BN -> hout (bf16); rows always < NN (no tail)
    #pragma unroll
    for (int nt = 0; nt < 2; ++nt) {
        int col = colbase + nt * 16 + l15;
        float bv = b2[col];
        float ga = gamma[col];
        float be = beta[col];
        float mu = rmean[col];
        float inv = rsqrtf(rvar[col] + 1e-5f);
        #pragma unroll
        for (int r = 0; r < 4; ++r) {
            int zr = kq * 4 + r;
            float v = acc4[nt][r] + bv;
            v = v > 0.f ? v : 0.f;
            v = (v - mu) * inv * ga + be;
            hout[(size_t)(row0 + zr) * DD + col] = f2bf(v);
        }
    }
#undef ACC8
}

// ---------------- pool (sorted batch -> segment sums) + final linear ----------------
__global__ __launch_bounds__(256) void pool_final(const unsigned short* __restrict__ h,
                                                  const int* __restrict__ batch,
                                                  const float* __restrict__ W,
                                                  const float* __restrict__ b,
                                                  float* __restrict__ out) {
    int g = blockIdx.x;           // one block per graph
    int t = threadIdx.x;
    int c2 = t & 63;              // col pair 2*c2, 2*c2+1
    int qu = t >> 6;              // row strand 0..3

    int lo = 0, hi = NN;
    while (lo < hi) { int mid = (lo + hi) >> 1; if (batch[mid] < g) lo = mid + 1; else hi = mid; }
    int start = lo;
    hi = NN;
    while (lo < hi) { int mid = (lo + hi) >> 1; if (batch[mid] < g + 1) lo = mid + 1; else hi = mid; }
    int end = lo;

    float ax = 0.f, ay = 0.f;
    for (int i = start + qu; i < end; i += 4) {
        unsigned u = *reinterpret_cast<const unsigned*>(h + (size_t)i * DD + c2 * 2);
        ax += bflo(u); ay += bfhi(u);
    }

    __shared__ float ps[4][DD];
    ps[qu][c2 * 2] = ax;
    ps[qu][c2 * 2 + 1] = ay;
    __syncthreads();
    if (t < DD) {
        float inv = 1.0f / fmaxf((float)(end - start), 1.0f);
        ps[0][t] = (ps[0][t] + ps[1][t] + ps[2][t] + ps[3][t]) * inv;
    }
    __syncthreads();
    if (t < DD) {
        float o = b[t];
        #pragma unroll 8
        for (int k = 0; k < DD; ++k)
            o += ps[0][k] * W[k * DD + t];
        out[(size_t)g * DD + t] = fmaxf(o, 0.f);
    }
}

extern "C" void kernel_launch(void* const* d_in, const int* in_sizes, int n_in,
                              void* d_out, int out_size, void* d_ws, size_t ws_size,
                              hipStream_t stream) {
    const float* x     = (const float*)d_in[0];
    const int*   ei    = (const int*)d_in[1];
    const int*   batch = (const int*)d_in[2];
    const float* W1    = (const float*)d_in[3];
    const float* b1    = (const float*)d_in[4];
    const float* W2    = (const float*)d_in[5];
    const float* b2    = (const float*)d_in[6];
    const float* gamma = (const float*)d_in[7];
    const float* beta  = (const float*)d_in[8];
    const float* rmean = (const float*)d_in[9];
    const float* rvar  = (const float*)d_in[10];
    const float* eps   = (const float*)d_in[11];
    const float* lin1W = (const float*)d_in[12];
    const float* lin1b = (const float*)d_in[13];
    float* out = (float*)d_out;

    char* ws = (char*)d_ws;
    size_t off = 0;
    auto alloc = [&](size_t bytes) {
        void* p = ws + off;
        off = (off + bytes + 255) & ~(size_t)255;
        return p;
    };
    unsigned short* h0  = (unsigned short*)alloc((size_t)(NN + 1) * DD * 2);
    unsigned short* h1  = (unsigned short*)alloc((size_t)(NN + 1) * DD * 2);
    int* rp   = (int*)alloc((size_t)(NN + 1) * 4);
    int* deg  = (int*)alloc((size_t)NN * 4);
    int* cnt  = (int*)alloc((size_t)NN * 4);
    int* part = (int*)alloc(512 * 4);
    int* csr  = (int*)alloc((size_t)CSRP * 4);
    unsigned short* wbf = (unsigned short*)alloc((size_t)NL * 2 * DD * DD * 2);

    init_all<<<INIT_BLKS, 256, 0, stream>>>(x, h0, h1, W1, W2, wbf, deg);

    hist_deg<<<NE / 256, 256, 0, stream>>>(ei, deg);
    scan1<<<NBLK, 256, 0, stream>>>(deg, rp, part);
    scan2<<<1, 512, 0, stream>>>(part);
    scan3<<<NBLK, 256, 0, stream>>>(rp, part, deg, cnt, csr);
    fill_csr<<<NE / 256, 256, 0, stream>>>(ei, rp, cnt, csr);

    const int lgrid = NN / 16;   // 6250, exact
    layer_fused<<<lgrid, 256, 0, stream>>>(
        h0, rp, csr, wbf + 0 * DD * DD, wbf + 1 * DD * DD,
        b1 + 0 * DD, b2 + 0 * DD, gamma + 0 * DD, beta + 0 * DD,
        rmean + 0 * DD, rvar + 0 * DD, eps + 0, h1);
    layer_fused<<<lgrid, 256, 0, stream>>>(
        h1, rp, csr, wbf + 2 * DD * DD, wbf + 3 * DD * DD,
        b1 + 1 * DD, b2 + 1 * DD, gamma + 1 * DD, beta + 1 * DD,
        rmean + 1 * DD, rvar + 1 * DD, eps + 1, h0);
    layer_fused<<<lgrid, 256, 0, stream>>>(
        h0, rp, csr, wbf + 4 * DD * DD, wbf + 5 * DD * DD,
        b1 + 2 * DD, b2 + 2 * DD, gamma + 2 * DD, beta + 2 * DD,
        rmean + 2 * DD, rvar + 2 * DD, eps + 2, h1);

    pool_final<<<NG, 256, 0, stream>>>(h1, batch, lin1W, lin1b, out);
}

// Round 7
// 551.089 us; speedup vs baseline: 15.6202x; 1.1099x over previous
//
#include <hip/hip_runtime.h>
#include <hip/hip_bf16.h>

#define NN 100000
#define NE 1600000
#define DD 128
#define NL 3
#define NG 512
#define NBLK ((NN + 255) / 256)        // 391 scan blocks
#define CSRP (NE + 8 * NN)             // padded CSR capacity (ints) = 2.4M

// fused init kernel block ranges (256 threads each)
#define CONV_BLKS 12501                // (NN+1)*DD/4 threads
#define PREPW_BLKS 384                 // NL*2*DD*DD/256
#define DEG_BLKS  391                  // NN/256
#define INIT_BLKS (CONV_BLKS + PREPW_BLKS + DEG_BLKS)

typedef __attribute__((ext_vector_type(8))) short bf16x8;
typedef __attribute__((ext_vector_type(4))) float f32x4;

__device__ __forceinline__ unsigned short f2bf(float f) {
    union { float f; unsigned int u; } x; x.f = f;
    unsigned int r = x.u + 0x7FFFu + ((x.u >> 16) & 1u);
    return (unsigned short)(r >> 16);
}
__device__ __forceinline__ float bf2f(unsigned short u) {
    union { unsigned int u; float f; } x; x.u = ((unsigned int)u) << 16;
    return x.f;
}
__device__ __forceinline__ float bflo(unsigned int v) { return bf2f((unsigned short)(v & 0xffffu)); }
__device__ __forceinline__ float bfhi(unsigned int v) { return bf2f((unsigned short)(v >> 16)); }
__device__ __forceinline__ unsigned cvtpk(float lo, float hi) {
    unsigned r;
    asm("v_cvt_pk_bf16_f32 %0, %1, %2" : "=v"(r) : "v"(lo), "v"(hi));
    return r;
}

// -------- fused init: conv_x | prep_w | deg=0 --------
__global__ __launch_bounds__(256) void init_all(const float* __restrict__ x,
                                                unsigned short* __restrict__ h0,
                                                unsigned short* __restrict__ h1,
                                                const float* __restrict__ W1,
                                                const float* __restrict__ W2,
                                                unsigned short* __restrict__ wbf,
                                                int* __restrict__ deg) {
    int bb = blockIdx.x;
    if (bb < CONV_BLKS) {
        long long t = (long long)bb * 256 + threadIdx.x;
        long long base = t * 4;
        if (base < (long long)NN * DD) {
            float4 v = *reinterpret_cast<const float4*>(x + base);
            ushort4 p;
            p.x = f2bf(v.x); p.y = f2bf(v.y); p.z = f2bf(v.z); p.w = f2bf(v.w);
            *reinterpret_cast<ushort4*>(h0 + base) = p;
        } else if (base < (long long)(NN + 1) * DD) {
            ushort4 z = {0, 0, 0, 0};
            *reinterpret_cast<ushort4*>(h0 + base) = z;
            *reinterpret_cast<ushort4*>(h1 + base) = z;
        }
        return;
    }
    bb -= CONV_BLKS;
    if (bb < PREPW_BLKS) {
        int idx = bb * 256 + threadIdx.x;            // < NL*2*DD*DD
        int k = idx & 127;
        int n = (idx >> 7) & 127;
        int w = (idx >> 14) & 1;
        int l = idx >> 15;
        const float* src = w ? W2 : W1;
        wbf[idx] = f2bf(src[(l * DD + k) * DD + n]);
        return;
    }
    bb -= PREPW_BLKS;
    int i = bb * 256 + threadIdx.x;
    if (i < NN) deg[i] = 0;
}

// ---------------- CSR build (once per call) ----------------
__global__ __launch_bounds__(256) void hist_deg(const int* __restrict__ ei,
                                                int* __restrict__ deg) {
    unsigned int e = blockIdx.x * 256u + threadIdx.x;   // < NE
    atomicAdd(&deg[ei[NE + e]], 1);
}

// scan over PADDED degrees: pdeg = ceil(deg/8)*8
__global__ __launch_bounds__(256) void scan1(const int* __restrict__ deg,
                                             int* __restrict__ rp,
                                             int* __restrict__ part) {
    __shared__ int s[256];
    int tid = threadIdx.x;
    int i = blockIdx.x * 256 + tid;
    int v = 0;
    if (i < NN) v = (deg[i] + 7) & ~7;
    s[tid] = v;
    __syncthreads();
    for (int o = 1; o < 256; o <<= 1) {
        int t = (tid >= o) ? s[tid - o] : 0;
        __syncthreads();
        s[tid] += t;
        __syncthreads();
    }
    if (i < NN) rp[i] = s[tid] - v;
    if (tid == 255) part[blockIdx.x] = s[255];
}

// merged scan2+scan3: each block computes its own prefix over part[],
// finalizes rp, zeroes cnt, writes ONLY pad slots (deg..pdeg) with NN
__global__ __launch_bounds__(256) void scan23(int* __restrict__ rp,
                                              const int* __restrict__ part,
                                              const int* __restrict__ deg,
                                              int* __restrict__ cnt,
                                              int* __restrict__ csr) {
    __shared__ int red[256];
    int tid = threadIdx.x;
    int bid = blockIdx.x;
    int s = 0;
    for (int i = tid; i < bid; i += 256) s += part[i];
    red[tid] = s;
    __syncthreads();
    for (int o = 128; o > 0; o >>= 1) {
        if (tid < o) red[tid] += red[tid + o];
        __syncthreads();
    }
    int base = red[0];
    int i = bid * 256 + tid;
    if (i < NN) {
        int val = rp[i] + base;
        rp[i] = val;
        cnt[i] = 0;
        int d = deg[i];
        int pd = (d + 7) & ~7;
        for (int j = val + d; j < val + pd; ++j) csr[j] = NN;
        if (i == NN - 1) rp[NN] = val + pd;
    }
}

__global__ __launch_bounds__(256) void fill_csr(const int* __restrict__ ei,
                                                const int* __restrict__ rp,
                                                int* __restrict__ cnt,
                                                int* __restrict__ csr) {
    unsigned int e = blockIdx.x * 256u + threadIdx.x;   // < NE
    int s = ei[e];
    int d = ei[NE + e];
    int pos = atomicAdd(&cnt[d], 1);
    csr[rp[d] + pos] = s;
}

// ---------------- fused layer: gather-agg + MLP + BN ----------------
// 16 rows/block (NN = 6250*16 exactly, no tail). 4 waves:
//  gather: each 16-lane group owns ONE row; 8 neighbor-row loads in flight
//          per group per iteration; no cross-lane reduce at all.
//  MFMA:   wave w -> 32-col slice of the 16x128 tile; 8 MFMAs per matmul.
__global__ __launch_bounds__(256) void layer_fused(
    const unsigned short* __restrict__ hin,   // (NN+1) rows, row NN = zeros
    const int* __restrict__ rp,               // padded row ptr (8-aligned)
    const int* __restrict__ csr,              // padded neighbor lists
    const unsigned short* __restrict__ w1t,   // [n][k] bf16
    const unsigned short* __restrict__ w2t,   // [n][k] bf16
    const float* __restrict__ b1,
    const float* __restrict__ b2,
    const float* __restrict__ gamma,
    const float* __restrict__ beta,
    const float* __restrict__ rmean,
    const float* __restrict__ rvar,
    const float* __restrict__ epsv,
    unsigned short* __restrict__ hout)
{
    __shared__ unsigned short z_lds[16 * 136];   // 4.35 KB
    const int tid = threadIdx.x;
    const int lane = tid & 63;
    const int wave = tid >> 6;
    const int gid = lane >> 4;        // group 0..3, owns one row
    const int lg = lane & 15;         // 16B feature slice within group
    const int row0 = blockIdx.x * 16;
    const float epl = 1.0f + epsv[0];
    const size_t lgo = (size_t)lg * 8;

#define ACC8(v) do { \
    acc[0] += bflo((v).x); acc[1] += bfhi((v).x); \
    acc[2] += bflo((v).y); acc[3] += bfhi((v).y); \
    acc[4] += bflo((v).z); acc[5] += bfhi((v).z); \
    acc[6] += bflo((v).w); acc[7] += bfhi((v).w); } while (0)

    // Phase 1: gather-aggregate; group g of wave w owns row w*4+g
    const int rbase = row0 + (wave << 2);
    int pv = (lane < 5) ? rp[rbase + lane] : 0;   // 5 rowptrs
    const int st = __shfl(pv, gid);
    const int en = __shfl(pv, gid + 1);
    const int myrow = rbase + gid;

    float acc[8];
    {
        uint4 sv = *reinterpret_cast<const uint4*>(hin + (size_t)myrow * DD + lgo);
        acc[0] = epl * bflo(sv.x); acc[1] = epl * bfhi(sv.x);
        acc[2] = epl * bflo(sv.y); acc[3] = epl * bfhi(sv.y);
        acc[4] = epl * bflo(sv.z); acc[5] = epl * bfhi(sv.z);
        acc[6] = epl * bflo(sv.w); acc[7] = epl * bfhi(sv.w);
    }
    for (int c0 = st; c0 < en; c0 += 8) {
        // group-uniform broadcast loads of 8 neighbor ids
        int4 idA = *reinterpret_cast<const int4*>(csr + c0);
        int4 idB = *reinterpret_cast<const int4*>(csr + c0 + 4);
        uint4 v0 = *reinterpret_cast<const uint4*>(hin + (size_t)idA.x * DD + lgo);
        uint4 v1 = *reinterpret_cast<const uint4*>(hin + (size_t)idA.y * DD + lgo);
        uint4 v2 = *reinterpret_cast<const uint4*>(hin + (size_t)idA.z * DD + lgo);
        uint4 v3 = *reinterpret_cast<const uint4*>(hin + (size_t)idA.w * DD + lgo);
        uint4 v4 = *reinterpret_cast<const uint4*>(hin + (size_t)idB.x * DD + lgo);
        uint4 v5 = *reinterpret_cast<const uint4*>(hin + (size_t)idB.y * DD + lgo);
        uint4 v6 = *reinterpret_cast<const uint4*>(hin + (size_t)idB.z * DD + lgo);
        uint4 v7 = *reinterpret_cast<const uint4*>(hin + (size_t)idB.w * DD + lgo);
        ACC8(v0); ACC8(v1); ACC8(v2); ACC8(v3);
        ACC8(v4); ACC8(v5); ACC8(v6); ACC8(v7);
    }
    {
        uint4 pk;
        pk.x = cvtpk(acc[0], acc[1]);
        pk.y = cvtpk(acc[2], acc[3]);
        pk.z = cvtpk(acc[4], acc[5]);
        pk.w = cvtpk(acc[6], acc[7]);
        *reinterpret_cast<uint4*>(&z_lds[((wave << 2) + gid) * 136 + lg * 8]) = pk;
    }
    __syncthreads();

    const int l15 = lane & 15;
    const int kq = lane >> 4;
    const int colbase = wave << 5;     // 32-col slice per wave

    // Matmul 1 (B-fragments straight from global; 32 KB weight is L1/L2-hot)
    bf16x8 afr[4];
    #pragma unroll
    for (int kk = 0; kk < 4; ++kk)
        afr[kk] = *reinterpret_cast<const bf16x8*>(&z_lds[l15 * 136 + kk * 32 + kq * 8]);

    f32x4 acc4[2];
    #pragma unroll
    for (int nt = 0; nt < 2; ++nt) acc4[nt] = (f32x4){0.f, 0.f, 0.f, 0.f};
    #pragma unroll
    for (int nt = 0; nt < 2; ++nt) {
        #pragma unroll
        for (int kk = 0; kk < 4; ++kk) {
            bf16x8 bfr = *reinterpret_cast<const bf16x8*>(
                w1t + (colbase + nt * 16 + l15) * DD + kk * 32 + kq * 8);
            acc4[nt] = __builtin_amdgcn_mfma_f32_16x16x32_bf16(afr[kk], bfr, acc4[nt], 0, 0, 0);
        }
    }
    __syncthreads();   // all afr reads done before epi1 writes (tile shared by all waves)

    // Epilogue 1: bias+relu, z1 -> z_lds (own 32-col slice, rows 0..15)
    #pragma unroll
    for (int nt = 0; nt < 2; ++nt) {
        int col = colbase + nt * 16 + l15;
        float bv = b1[col];
        #pragma unroll
        for (int r = 0; r < 4; ++r) {
            int zr = kq * 4 + r;
            float v = acc4[nt][r] + bv;
            v = v > 0.f ? v : 0.f;
            z_lds[zr * 136 + col] = f2bf(v);
        }
    }
    __syncthreads();

    // Matmul 2
    #pragma unroll
    for (int kk = 0; kk < 4; ++kk)
        afr[kk] = *reinterpret_cast<const bf16x8*>(&z_lds[l15 * 136 + kk * 32 + kq * 8]);
    #pragma unroll
    for (int nt = 0; nt < 2; ++nt) acc4[nt] = (f32x4){0.f, 0.f, 0.f, 0.f};
    #pragma unroll
    for (int nt = 0; nt < 2; ++nt) {
        #pragma unroll
        for (int kk = 0; kk < 4; ++kk) {
            bf16x8 bfr = *reinterpret_cast<const bf16x8*>(
                w2t + (colbase + nt * 16 + l15) * DD + kk * 32 + kq * 8);
            acc4[nt] = __builtin_amdgcn_mfma_f32_16x16x32_bf16(afr[kk], bfr, acc4[nt], 0, 0, 0);
        }
    }

    // Epilogue 2: bias+relu+BN -> hout (bf16); rows always < NN (no tail)
    #pragma unroll
    for (int nt = 0; nt < 2; ++nt) {
        int col = colbase + nt * 16 + l15;
        float bv = b2[col];
        float ga = gamma[col];
        float be = beta[col];
        float mu = rmean[col];
        float inv = rsqrtf(rvar[col] + 1e-5f);
        #pragma unroll
        for (int r = 0; r < 4; ++r) {
            int zr = kq * 4 + r;
            float v = acc4[nt][r] + bv;
            v = v > 0.f ? v : 0.f;
            v = (v - mu) * inv * ga + be;
            hout[(size_t)(row0 + zr) * DD + col] = f2bf(v);
        }
    }
#undef ACC8
}

// ---------------- pool (sorted batch -> segment sums) + final linear ----------------
__global__ __launch_bounds__(256) void pool_final(const unsigned short* __restrict__ h,
                                                  const int* __restrict__ batch,
                                                  const float* __restrict__ W,
                                                  const float* __restrict__ b,
                                                  float* __restrict__ out) {
    int g = blockIdx.x;           // one block per graph
    int t = threadIdx.x;
    int c2 = t & 63;              // col pair 2*c2, 2*c2+1
    int qu = t >> 6;              // row strand 0..3

    int lo = 0, hi = NN;
    while (lo < hi) { int mid = (lo + hi) >> 1; if (batch[mid] < g) lo = mid + 1; else hi = mid; }
    int start = lo;
    hi = NN;
    while (lo < hi) { int mid = (lo + hi) >> 1; if (batch[mid] < g + 1) lo = mid + 1; else hi = mid; }
    int end = lo;

    float ax = 0.f, ay = 0.f;
    for (int i = start + qu; i < end; i += 4) {
        unsigned u = *reinterpret_cast<const unsigned*>(h + (size_t)i * DD + c2 * 2);
        ax += bflo(u); ay += bfhi(u);
    }

    __shared__ float ps[4][DD];
    ps[qu][c2 * 2] = ax;
    ps[qu][c2 * 2 + 1] = ay;
    __syncthreads();
    if (t < DD) {
        float inv = 1.0f / fmaxf((float)(end - start), 1.0f);
        ps[0][t] = (ps[0][t] + ps[1][t] + ps[2][t] + ps[3][t]) * inv;
    }
    __syncthreads();
    if (t < DD) {
        float o = b[t];
        #pragma unroll 8
        for (int k = 0; k < DD; ++k)
            o += ps[0][k] * W[k * DD + t];
        out[(size_t)g * DD + t] = fmaxf(o, 0.f);
    }
}

extern "C" void kernel_launch(void* const* d_in, const int* in_sizes, int n_in,
                              void* d_out, int out_size, void* d_ws, size_t ws_size,
                              hipStream_t stream) {
    const float* x     = (const float*)d_in[0];
    const int*   ei    = (const int*)d_in[1];
    const int*   batch = (const int*)d_in[2];
    const float* W1    = (const float*)d_in[3];
    const float* b1    = (const float*)d_in[4];
    const float* W2    = (const float*)d_in[5];
    const float* b2    = (const float*)d_in[6];
    const float* gamma = (const float*)d_in[7];
    const float* beta  = (const float*)d_in[8];
    const float* rmean = (const float*)d_in[9];
    const float* rvar  = (const float*)d_in[10];
    const float* eps   = (const float*)d_in[11];
    const float* lin1W = (const float*)d_in[12];
    const float* lin1b = (const float*)d_in[13];
    float* out = (float*)d_out;

    char* ws = (char*)d_ws;
    size_t off = 0;
    auto alloc = [&](size_t bytes) {
        void* p = ws + off;
        off = (off + bytes + 255) & ~(size_t)255;
        return p;
    };
    unsigned short* h0  = (unsigned short*)alloc((size_t)(NN + 1) * DD * 2);
    unsigned short* h1  = (unsigned short*)alloc((size_t)(NN + 1) * DD * 2);
    int* rp   = (int*)alloc((size_t)(NN + 1) * 4);
    int* deg  = (int*)alloc((size_t)NN * 4);
    int* cnt  = (int*)alloc((size_t)NN * 4);
    int* part = (int*)alloc(512 * 4);
    int* csr  = (int*)alloc((size_t)CSRP * 4);
    unsigned short* wbf = (unsigned short*)alloc((size_t)NL * 2 * DD * DD * 2);

    init_all<<<INIT_BLKS, 256, 0, stream>>>(x, h0, h1, W1, W2, wbf, deg);

    hist_deg<<<NE / 256, 256, 0, stream>>>(ei, deg);
    scan1<<<NBLK, 256, 0, stream>>>(deg, rp, part);
    scan23<<<NBLK, 256, 0, stream>>>(rp, part, deg, cnt, csr);
    fill_csr<<<NE / 256, 256, 0, stream>>>(ei, rp, cnt, csr);

    const int lgrid = NN / 16;   // 6250, exact
    layer_fused<<<lgrid, 256, 0, stream>>>(
        h0, rp, csr, wbf + 0 * DD * DD, wbf + 1 * DD * DD,
        b1 + 0 * DD, b2 + 0 * DD, gamma + 0 * DD, beta + 0 * DD,
        rmean + 0 * DD, rvar + 0 * DD, eps + 0, h1);
    layer_fused<<<lgrid, 256, 0, stream>>>(
        h1, rp, csr, wbf + 2 * DD * DD, wbf + 3 * DD * DD,
        b1 + 1 * DD, b2 + 1 * DD, gamma + 1 * DD, beta + 1 * DD,
        rmean + 1 * DD, rvar + 1 * DD, eps + 1, h0);
    layer_fused<<<lgrid, 256, 0, stream>>>(
        h0, rp, csr, wbf + 4 * DD * DD, wbf + 5 * DD * DD,
        b1 + 2 * DD, b2 + 2 * DD, gamma + 2 * DD, beta + 2 * DD,
        rmean + 2 * DD, rvar + 2 * DD, eps + 2, h1);

    pool_final<<<NG, 256, 0, stream>>>(h1, batch, lin1W, lin1b, out);
}